// Round 4
// baseline (247.448 us; speedup 1.0000x reference)
//
#include <hip/hip_runtime.h>
#include <math.h>

#define B_    4
#define SEQ_  2048
#define S_    128
#define L_    2304          // SEQ + 2*S
#define DIN   512
#define DK    64
#define NEGINF (-1e30f)
#define SCALE 0.125f
#define NMID  8192          // B_*SEQ_
#define NEDGE 1024          // B_*2*S_
#define LE    2304          // edge De row length

typedef _Float16 f16;
typedef __attribute__((ext_vector_type(8))) _Float16 half8;
typedef __attribute__((ext_vector_type(4))) float f32x4;

union U4 { uint4 u; f16 h[8]; };

// ---------------------------------------------------------------------------
// k_wsplit: pre-split 9 W matrices into fp16 hi/lo (transposed) + cope split.
// grid (8, 10) x 256. mat==9: cope (64x128) -> copesp[p][hi d | lo d].
// ---------------------------------------------------------------------------
__global__ __launch_bounds__(256) void k_wsplit(
    const float* __restrict__ Wq,  const float* __restrict__ Wk,  const float* __restrict__ Wv,
    const float* __restrict__ Wqs, const float* __restrict__ Wks, const float* __restrict__ Wvs,
    const float* __restrict__ Wqe, const float* __restrict__ Wke, const float* __restrict__ Wve,
    const float* __restrict__ cope,
    f16* __restrict__ Wsp, f16* __restrict__ copesp)
{
    __shared__ float xs[64 * 68];
    const int kt  = blockIdx.x;
    const int mat = blockIdx.y;
    const int tid = threadIdx.x;

    if (mat == 9) {
        if (kt != 0) return;
        for (int half = 0; half < 2; ++half) {
            #pragma unroll
            for (int i = 0; i < 4; ++i) {
                int g = tid + 256 * i;          // 64 d x 16 float4
                int d = g >> 4, p4 = g & 15;
                *(float4*)(xs + d * 68 + p4 * 4) =
                    *(const float4*)(cope + (size_t)d * 128 + half * 64 + p4 * 4);
            }
            __syncthreads();
            if (tid < 128) {
                int pp = tid & 63, hf = tid >> 6;   // 2 halves of d
                int d0 = hf * 32;
                for (int j = 0; j < 32; ++j) {
                    float v = xs[(d0 + j) * 68 + pp];
                    f16 hi = (f16)v;
                    copesp[(size_t)(half * 64 + pp) * 128 + d0 + j]      = hi;
                    copesp[(size_t)(half * 64 + pp) * 128 + 64 + d0 + j] = (f16)(v - (float)hi);
                }
            }
            __syncthreads();
        }
        return;
    }

    const float* W;
    switch (mat) {
        case 0: W = Wq;  break; case 1: W = Wk;  break; case 2: W = Wv;  break;
        case 3: W = Wqs; break; case 4: W = Wks; break; case 5: W = Wvs; break;
        case 6: W = Wqe; break; case 7: W = Wke; break; default: W = Wve; break;
    }
    const int k0  = kt * 64;
    #pragma unroll
    for (int i = 0; i < 4; ++i) {
        int g = tid + 256 * i;
        int k = g >> 4, c4 = g & 15;
        *(float4*)(xs + k * 68 + c4 * 4) = ((const float4*)W)[(size_t)(k0 + k) * 16 + c4];
    }
    __syncthreads();
    const int col = tid & 63, hf = tid >> 6;
    const int kk0 = hf * 16;
    U4 hi0, hi1, lo0, lo1;
    #pragma unroll
    for (int j = 0; j < 8; ++j) {
        float v0 = xs[(kk0 + j) * 68 + col];
        float v1 = xs[(kk0 + 8 + j) * 68 + col];
        hi0.h[j] = (f16)v0; lo0.h[j] = (f16)(v0 - (float)hi0.h[j]);
        hi1.h[j] = (f16)v1; lo1.h[j] = (f16)(v1 - (float)hi1.h[j]);
    }
    f16* dst = Wsp + (size_t)mat * 65536 + (size_t)col * 1024 + k0 + kk0;
    *(uint4*)(dst)       = hi0.u;
    *(uint4*)(dst + 8)   = hi1.u;
    *(uint4*)(dst + 512) = lo0.u;
    *(uint4*)(dst + 520) = lo1.u;
}

// ---------------------------------------------------------------------------
// k_proj: fused LayerNorm + q,k,v projections. grid 288 x 256.
// ---------------------------------------------------------------------------
__global__ __launch_bounds__(256) void k_proj(
    const float* __restrict__ x, const f16* __restrict__ Wsp,
    const float* __restrict__ g0, const float* __restrict__ b0,
    const float* __restrict__ gs, const float* __restrict__ bs,
    const float* __restrict__ ge, const float* __restrict__ be,
    f16* __restrict__ qsp, f16* __restrict__ ksp, f16* __restrict__ vhT)
{
    __shared__ f16 As[32 * 136];
    __shared__ f16 Bs[3 * 64 * 136];
    __shared__ float mean_s[32], rstd_s[32];
    const int tid  = threadIdx.x;
    const int row0 = blockIdx.x * 32;
    const int rseq = row0 % L_;
    const int seg  = (rseq < S_) ? 0 : (rseq >= L_ - S_) ? 2 : 1;
    const int mat0 = (seg == 0) ? 3 : (seg == 2) ? 6 : 0;
    const float* gg = (seg == 0) ? gs : (seg == 2) ? ge : g0;
    const float* bb = (seg == 0) ? bs : (seg == 2) ? be : b0;

    {
        const int rr = tid >> 3, qq = tid & 7;
        const float4* xr = (const float4*)(x + (size_t)(row0 + rr) * DIN) + qq * 16;
        float s = 0.f, s2 = 0.f;
        #pragma unroll
        for (int i = 0; i < 16; ++i) {
            float4 v = xr[i];
            s  += v.x + v.y + v.z + v.w;
            s2 += v.x * v.x + v.y * v.y + v.z * v.z + v.w * v.w;
        }
        s  += __shfl_xor(s, 1);  s  += __shfl_xor(s, 2);  s  += __shfl_xor(s, 4);
        s2 += __shfl_xor(s2, 1); s2 += __shfl_xor(s2, 2); s2 += __shfl_xor(s2, 4);
        if (qq == 0) {
            float mean = s * (1.f / DIN);
            mean_s[rr] = mean;
            rstd_s[rr] = rsqrtf(s2 * (1.f / DIN) - mean * mean + 1e-5f);
        }
    }

    const int w = tid >> 6, lane = tid & 63;
    const int cl = lane & 15, quad = lane >> 4;
    const int r0 = 16 * (w >> 1), c0 = 32 * (w & 1);

    f32x4 acc[3][2];
    #pragma unroll
    for (int m = 0; m < 3; ++m)
        #pragma unroll
        for (int j = 0; j < 2; ++j) acc[m][j] = 0.f;

    for (int kc = 0; kc < DIN; kc += 64) {
        __syncthreads();
        {
            int r = tid >> 3, c8 = tid & 7;
            const float* xp = x + (size_t)(row0 + r) * DIN + kc + c8 * 8;
            float4 a0 = *(const float4*)xp;
            float4 a1 = *(const float4*)(xp + 4);
            float4 gA = *(const float4*)(gg + kc + c8 * 8);
            float4 gB = *(const float4*)(gg + kc + c8 * 8 + 4);
            float4 bA = *(const float4*)(bb + kc + c8 * 8);
            float4 bB = *(const float4*)(bb + kc + c8 * 8 + 4);
            float mean = mean_s[r], rstd = rstd_s[r];
            float n[8];
            n[0] = (a0.x - mean) * rstd * gA.x + bA.x;
            n[1] = (a0.y - mean) * rstd * gA.y + bA.y;
            n[2] = (a0.z - mean) * rstd * gA.z + bA.z;
            n[3] = (a0.w - mean) * rstd * gA.w + bA.w;
            n[4] = (a1.x - mean) * rstd * gB.x + bB.x;
            n[5] = (a1.y - mean) * rstd * gB.y + bB.y;
            n[6] = (a1.z - mean) * rstd * gB.z + bB.z;
            n[7] = (a1.w - mean) * rstd * gB.w + bB.w;
            U4 hi, lo;
            #pragma unroll
            for (int j = 0; j < 8; ++j) {
                hi.h[j] = (f16)n[j];
                lo.h[j] = (f16)(n[j] - (float)hi.h[j]);
            }
            *(uint4*)(As + r * 136 + c8 * 8)      = hi.u;
            *(uint4*)(As + r * 136 + 64 + c8 * 8) = lo.u;
        }
        #pragma unroll
        for (int i = 0; i < 6; ++i) {
            int g = tid + 256 * i;
            int mm = g >> 9, rem = g & 511;
            int col = rem >> 3, c8 = rem & 7;
            const f16* src = Wsp + (size_t)(mat0 + mm) * 65536 + (size_t)col * 1024 + kc + c8 * 8;
            f16* dst = Bs + mm * 8704 + col * 136 + c8 * 8;
            *(uint4*)(dst)      = *(const uint4*)(src);
            *(uint4*)(dst + 64) = *(const uint4*)(src + 512);
        }
        __syncthreads();
        #pragma unroll
        for (int h = 0; h < 2; ++h) {
            half8 ah, al;
            {
                const f16* base = As + (r0 + cl) * 136 + h * 32 + quad * 8;
                ah = *(const half8*)(base);
                al = *(const half8*)(base + 64);
            }
            #pragma unroll
            for (int m = 0; m < 3; ++m)
                #pragma unroll
                for (int cs = 0; cs < 2; ++cs) {
                    const f16* base = Bs + m * 8704 + (c0 + 16 * cs + cl) * 136 + h * 32 + quad * 8;
                    half8 bh = *(const half8*)(base);
                    half8 bl = *(const half8*)(base + 64);
                    acc[m][cs] = __builtin_amdgcn_mfma_f32_16x16x32_f16(ah, bh, acc[m][cs], 0, 0, 0);
                    acc[m][cs] = __builtin_amdgcn_mfma_f32_16x16x32_f16(ah, bl, acc[m][cs], 0, 0, 0);
                    acc[m][cs] = __builtin_amdgcn_mfma_f32_16x16x32_f16(al, bh, acc[m][cs], 0, 0, 0);
                }
        }
    }

    const int bI = row0 / L_;
    const int rb = row0 - bI * L_;
    #pragma unroll
    for (int m = 0; m < 3; ++m) {
        f16* sp = (m == 0) ? qsp : ksp;
        #pragma unroll
        for (int cs = 0; cs < 2; ++cs)
            #pragma unroll
            for (int r = 0; r < 4; ++r) {
                int lrow = r0 + quad * 4 + r;
                int col  = c0 + 16 * cs + cl;
                float v  = acc[m][cs][r];
                size_t grow = (size_t)(row0 + lrow);
                if (m < 2) {
                    f16 hv = (f16)v;
                    sp[grow * 128 + col]      = hv;
                    sp[grow * 128 + 64 + col] = (f16)(v - (float)hv);
                } else {
                    vhT[(size_t)(bI * 64 + col) * L_ + rb + lrow] = (f16)v;
                }
            }
    }
}

// ---------------------------------------------------------------------------
// k_fmid v2: wave-parallel flash attention for mid rows.
// Block = 32 q-rows, 8 waves. Q in registers; K/V read directly from L2
// (no staging barriers). Phase 1: gate totals for the 16 mid tiles (2/wave).
// Phase 2: tile-suffix R. Phase 3: causal tiles round-robin per wave with
// order-independent online softmax; wave-private P chunk in LDS for PV.
// Final 8->1 merge of (m, l, accO). ~6 barriers per block total (was 85).
// ---------------------------------------------------------------------------
__global__ __launch_bounds__(512, 1) void k_fmid(
    const f16* __restrict__ qsp, const f16* __restrict__ ksp,
    const f16* __restrict__ vhT, const f16* __restrict__ copesp,
    float* __restrict__ out)
{
    __shared__ float li[32 * 132];      // [row][pos]
    __shared__ float Tt[16][32];        // per-tile gate totals
    __shared__ float Rr[16][32];        // suffix over tiles
    __shared__ float Mw[8][32], Lw[8][32];
    __shared__ f16   Ps[8][32 * 34];    // wave-private P chunk (32 rows x 32 k)
    __shared__ float obuf[4][32 * 66];  // merge tree buffers

    const int tid = threadIdx.x;
    const int w = tid >> 6, lane = tid & 63;
    const int cl = lane & 15, quad = lane >> 4;
    const int blk = blockIdx.x;
    const int b = blk >> 6, strip = blk & 63;
    const int q0 = strip * 32;
    const size_t rowbase = (size_t)b * L_ + S_ + q0;
    const int tmax = ((q0 + 31) >> 7) + 1;

    // Q A-fragments in registers (all 32 rows of the strip)
    half8 qh[2][2], ql[2][2];
    #pragma unroll
    for (int rs = 0; rs < 2; ++rs)
        #pragma unroll
        for (int h = 0; h < 2; ++h) {
            const f16* qp = qsp + (rowbase + 16 * rs + cl) * 128 + h * 32 + quad * 8;
            qh[rs][h] = *(const half8*)qp;
            ql[rs][h] = *(const half8*)(qp + 64);
        }

    // li = q . cope  (wave w: rows 16g, cols 32ch)
    {
        const int g = w >> 2, ch = w & 3;
        f32x4 accli[2];
        accli[0] = 0.f; accli[1] = 0.f;
        #pragma unroll
        for (int h = 0; h < 2; ++h)
            #pragma unroll
            for (int cf = 0; cf < 2; ++cf) {
                const f16* bbase = copesp + (size_t)(32 * ch + 16 * cf + cl) * 128 + h * 32 + quad * 8;
                half8 bh = *(const half8*)bbase;
                half8 bl = *(const half8*)(bbase + 64);
                accli[cf] = __builtin_amdgcn_mfma_f32_16x16x32_f16(qh[g][h], bh, accli[cf], 0, 0, 0);
                accli[cf] = __builtin_amdgcn_mfma_f32_16x16x32_f16(qh[g][h], bl, accli[cf], 0, 0, 0);
                accli[cf] = __builtin_amdgcn_mfma_f32_16x16x32_f16(ql[g][h], bh, accli[cf], 0, 0, 0);
            }
        #pragma unroll
        for (int cf = 0; cf < 2; ++cf)
            #pragma unroll
            for (int r = 0; r < 4; ++r)
                li[(16 * g + quad * 4 + r) * 132 + 32 * ch + 16 * cf + cl] = accli[cf][r];
    }

    // Phase 1: gate totals for mid tiles t = 1+w, 9+w (all tiles, no mask)
    #pragma unroll
    for (int pp = 0; pp < 2; ++pp) {
        const int t = 1 + w + 8 * pp;
        const size_t rowK = (size_t)b * L_ + S_ + 128 * (t - 1);
        f32x4 acc[2][8];
        #pragma unroll
        for (int i = 0; i < 2; ++i)
            #pragma unroll
            for (int j = 0; j < 8; ++j) acc[i][j] = 0.f;
        #pragma unroll
        for (int h = 0; h < 2; ++h)
            #pragma unroll
            for (int c = 0; c < 8; ++c) {
                const f16* kp = ksp + (rowK + 16 * c + cl) * 128 + h * 32 + quad * 8;
                half8 bh = *(const half8*)kp;
                half8 bl = *(const half8*)(kp + 64);
                #pragma unroll
                for (int rs = 0; rs < 2; ++rs) {
                    acc[rs][c] = __builtin_amdgcn_mfma_f32_16x16x32_f16(qh[rs][h], bh, acc[rs][c], 0, 0, 0);
                    acc[rs][c] = __builtin_amdgcn_mfma_f32_16x16x32_f16(qh[rs][h], bl, acc[rs][c], 0, 0, 0);
                    acc[rs][c] = __builtin_amdgcn_mfma_f32_16x16x32_f16(ql[rs][h], bh, acc[rs][c], 0, 0, 0);
                }
            }
        #pragma unroll
        for (int rs = 0; rs < 2; ++rs)
            #pragma unroll
            for (int r = 0; r < 4; ++r) {
                float s = 0.f;
                #pragma unroll
                for (int c = 0; c < 8; ++c)
                    s += 1.f / (1.f + __expf(-acc[rs][c][r]));
                s += __shfl_xor(s, 1, 16); s += __shfl_xor(s, 2, 16);
                s += __shfl_xor(s, 4, 16); s += __shfl_xor(s, 8, 16);
                if (cl == 0) Tt[t - 1][16 * rs + quad * 4 + r] = s;
            }
    }
    __syncthreads();

    // Phase 2: R[t] = sum of tile totals above t
    {
        int row = tid & 31, t = (tid >> 5) + 1;   // t in 1..16
        float s = 0.f;
        for (int u = t; u < 16; ++u) s += Tt[u][row];
        Rr[t - 1][row] = s;
    }
    __syncthreads();

    // Phase 3: causal tiles round-robin; online softmax + PV
    float m_w[2][4], l_w[2][4], tot1[2][4];
    f32x4 accO[2][4];
    #pragma unroll
    for (int rs = 0; rs < 2; ++rs)
        #pragma unroll
        for (int r = 0; r < 4; ++r) { m_w[rs][r] = NEGINF; l_w[rs][r] = 0.f; tot1[rs][r] = 0.f; }
    #pragma unroll
    for (int rs = 0; rs < 2; ++rs)
        #pragma unroll
        for (int c = 0; c < 4; ++c) accO[rs][c] = 0.f;

    for (int t = w; t <= tmax; t += 8) {
        const bool mid = (t >= 1);
        const int vbase = mid ? (S_ + 128 * (t - 1)) : 0;
        const size_t rowK = (size_t)b * L_ + vbase;
        float Rbase[2][4];
        if (mid) {
            #pragma unroll
            for (int rs = 0; rs < 2; ++rs)
                #pragma unroll
                for (int r = 0; r < 4; ++r)
                    Rbase[rs][r] = Rr[t - 1][16 * rs + quad * 4 + r];
        }
        #pragma unroll
        for (int hx = 1; hx >= 0; --hx) {
            const int cb = 4 * hx;
            f32x4 acc[2][4];
            #pragma unroll
            for (int i = 0; i < 2; ++i)
                #pragma unroll
                for (int j = 0; j < 4; ++j) acc[i][j] = 0.f;
            #pragma unroll
            for (int h = 0; h < 2; ++h)
                #pragma unroll
                for (int c = 0; c < 4; ++c) {
                    const f16* kp = ksp + (rowK + 16 * (cb + c) + cl) * 128 + h * 32 + quad * 8;
                    half8 bh = *(const half8*)kp;
                    half8 bl = *(const half8*)(kp + 64);
                    #pragma unroll
                    for (int rs = 0; rs < 2; ++rs) {
                        acc[rs][c] = __builtin_amdgcn_mfma_f32_16x16x32_f16(qh[rs][h], bh, acc[rs][c], 0, 0, 0);
                        acc[rs][c] = __builtin_amdgcn_mfma_f32_16x16x32_f16(qh[rs][h], bl, acc[rs][c], 0, 0, 0);
                        acc[rs][c] = __builtin_amdgcn_mfma_f32_16x16x32_f16(ql[rs][h], bh, acc[rs][c], 0, 0, 0);
                    }
                }

            float sfx[2][4][4];
            if (mid) {
                #pragma unroll
                for (int rs = 0; rs < 2; ++rs)
                    #pragma unroll
                    for (int c = 0; c < 4; ++c)
                        #pragma unroll
                        for (int r = 0; r < 4; ++r)
                            sfx[rs][c][r] = 1.f / (1.f + __expf(-acc[rs][c][r]));
                #pragma unroll
                for (int off = 1; off < 16; off <<= 1)
                    #pragma unroll
                    for (int rs = 0; rs < 2; ++rs)
                        #pragma unroll
                        for (int c = 0; c < 4; ++c)
                            #pragma unroll
                            for (int r = 0; r < 4; ++r) {
                                float u = __shfl_down(sfx[rs][c][r], off, 16);
                                if (cl + off < 16) sfx[rs][c][r] += u;
                            }
                #pragma unroll
                for (int rs = 0; rs < 2; ++rs)
                    #pragma unroll
                    for (int r = 0; r < 4; ++r) {
                        float tc0 = __shfl(sfx[rs][0][r], 0, 16);
                        float tc1 = __shfl(sfx[rs][1][r], 0, 16);
                        float tc2 = __shfl(sfx[rs][2][r], 0, 16);
                        float tc3 = __shfl(sfx[rs][3][r], 0, 16);
                        float run = 0.f;
                        sfx[rs][3][r] += run; run += tc3;
                        sfx[rs][2][r] += run; run += tc2;
                        sfx[rs][1][r] += run; run += tc1;
                        sfx[rs][0][r] += run; run += tc0;
                        if (hx == 1) tot1[rs][r] = run;
                    }
            }

            // scores (in place)
            #pragma unroll
            for (int rs = 0; rs < 2; ++rs)
                #pragma unroll
                for (int c = 0; c < 4; ++c)
                    #pragma unroll
                    for (int r = 0; r < 4; ++r) {
                        int row = 16 * rs + quad * 4 + r;
                        float v = acc[rs][c][r] * SCALE;
                        if (mid) {
                            float pos = sfx[rs][c][r] + Rbase[rs][r] + ((hx == 0) ? tot1[rs][r] : 0.f);
                            pos = fminf(pos, 127.f);
                            float pfl = floorf(pos);
                            int ic = (int)ceilf(pos), ifl = (int)pfl;
                            float wf = pos - pfl;
                            v += li[row * 132 + ic] * wf + li[row * 132 + ifl] * (1.f - wf);
                            int mcol = 128 * (t - 1) + 16 * (cb + c) + cl;
                            if (mcol > q0 + row) v = NEGINF;
                        }
                        acc[rs][c][r] = v;
                    }

            // online softmax update (wave-local)
            float scf[2][4];
            #pragma unroll
            for (int rs = 0; rs < 2; ++rs)
                #pragma unroll
                for (int r = 0; r < 4; ++r) {
                    float ml = fmaxf(fmaxf(acc[rs][0][r], acc[rs][1][r]),
                                     fmaxf(acc[rs][2][r], acc[rs][3][r]));
                    ml = fmaxf(ml, __shfl_xor(ml, 1, 16));
                    ml = fmaxf(ml, __shfl_xor(ml, 2, 16));
                    ml = fmaxf(ml, __shfl_xor(ml, 4, 16));
                    ml = fmaxf(ml, __shfl_xor(ml, 8, 16));
                    float mn = fmaxf(fmaxf(m_w[rs][r], ml), -1e28f);
                    scf[rs][r] = __expf(m_w[rs][r] - mn);
                    m_w[rs][r] = mn;
                }
            #pragma unroll
            for (int rs = 0; rs < 2; ++rs)
                #pragma unroll
                for (int c = 0; c < 4; ++c)
                    #pragma unroll
                    for (int r = 0; r < 4; ++r)
                        accO[rs][c][r] *= scf[rs][r];

            float lsum[2][4];
            #pragma unroll
            for (int rs = 0; rs < 2; ++rs)
                #pragma unroll
                for (int r = 0; r < 4; ++r) lsum[rs][r] = 0.f;
            #pragma unroll
            for (int rs = 0; rs < 2; ++rs)
                #pragma unroll
                for (int c = 0; c < 4; ++c)
                    #pragma unroll
                    for (int r = 0; r < 4; ++r) {
                        float e = __expf(acc[rs][c][r] - m_w[rs][r]);
                        acc[rs][c][r] = e;
                        lsum[rs][r] += e;
                    }
            #pragma unroll
            for (int rs = 0; rs < 2; ++rs)
                #pragma unroll
                for (int r = 0; r < 4; ++r) {
                    float s = lsum[rs][r];
                    s += __shfl_xor(s, 1, 16); s += __shfl_xor(s, 2, 16);
                    s += __shfl_xor(s, 4, 16); s += __shfl_xor(s, 8, 16);
                    l_w[rs][r] = l_w[rs][r] * scf[rs][r] + s;
                }

            // PV in two 32-col chunks (wave-private LDS bounce for transpose)
            #pragma unroll
            for (int kfl = 0; kfl < 2; ++kfl) {
                #pragma unroll
                for (int rs = 0; rs < 2; ++rs)
                    #pragma unroll
                    for (int cw = 0; cw < 2; ++cw)
                        #pragma unroll
                        for (int r = 0; r < 4; ++r)
                            Ps[w][(16 * rs + quad * 4 + r) * 34 + 16 * cw + cl] =
                                (f16)acc[rs][2 * kfl + cw][r];
                half8 pa[2];
                #pragma unroll
                for (int rs2 = 0; rs2 < 2; ++rs2)
                    pa[rs2] = *(const half8*)&Ps[w][(16 * rs2 + cl) * 34 + quad * 8];
                const int kf = 2 * hx + kfl;
                #pragma unroll
                for (int c2 = 0; c2 < 4; ++c2) {
                    const f16* vp = vhT + (size_t)(b * 64 + 16 * c2 + cl) * L_ + vbase + kf * 32 + quad * 8;
                    half8 bv = *(const half8*)vp;
                    #pragma unroll
                    for (int rs2 = 0; rs2 < 2; ++rs2)
                        accO[rs2][c2] = __builtin_amdgcn_mfma_f32_16x16x32_f16(pa[rs2], bv, accO[rs2][c2], 0, 0, 0);
                }
            }
        }
    }

    // merge 8 waves
    if (cl == 0) {
        #pragma unroll
        for (int rs = 0; rs < 2; ++rs)
            #pragma unroll
            for (int r = 0; r < 4; ++r) {
                Mw[w][16 * rs + quad * 4 + r] = m_w[rs][r];
                Lw[w][16 * rs + quad * 4 + r] = l_w[rs][r];
            }
    }
    __syncthreads();

    float lg[2][4];
    #pragma unroll
    for (int rs = 0; rs < 2; ++rs)
        #pragma unroll
        for (int r = 0; r < 4; ++r) {
            int row = 16 * rs + quad * 4 + r;
            float m = Mw[0][row];
            #pragma unroll
            for (int i = 1; i < 8; ++i) m = fmaxf(m, Mw[i][row]);
            float s = 0.f;
            #pragma unroll
            for (int i = 0; i < 8; ++i) s += Lw[i][row] * __expf(Mw[i][row] - m);
            lg[rs][r] = s;
            float scf = __expf(m_w[rs][r] - m);
            #pragma unroll
            for (int c = 0; c < 4; ++c) accO[rs][c][r] *= scf;
        }

    if (w >= 4) {
        #pragma unroll
        for (int rs = 0; rs < 2; ++rs)
            #pragma unroll
            for (int c = 0; c < 4; ++c)
                #pragma unroll
                for (int r = 0; r < 4; ++r)
                    obuf[w - 4][(16 * rs + quad * 4 + r) * 66 + 16 * c + cl] = accO[rs][c][r];
    }
    __syncthreads();
    if (w < 4) {
        #pragma unroll
        for (int rs = 0; rs < 2; ++rs)
            #pragma unroll
            for (int c = 0; c < 4; ++c)
                #pragma unroll
                for (int r = 0; r < 4; ++r)
                    accO[rs][c][r] += obuf[w][(16 * rs + quad * 4 + r) * 66 + 16 * c + cl];
        if (w >= 2) {
            #pragma unroll
            for (int rs = 0; rs < 2; ++rs)
                #pragma unroll
                for (int c = 0; c < 4; ++c)
                    #pragma unroll
                    for (int r = 0; r < 4; ++r)
                        obuf[w][(16 * rs + quad * 4 + r) * 66 + 16 * c + cl] = accO[rs][c][r];
        }
    }
    __syncthreads();
    if (w < 2) {
        #pragma unroll
        for (int rs = 0; rs < 2; ++rs)
            #pragma unroll
            for (int c = 0; c < 4; ++c)
                #pragma unroll
                for (int r = 0; r < 4; ++r)
                    accO[rs][c][r] += obuf[w + 2][(16 * rs + quad * 4 + r) * 66 + 16 * c + cl];
        if (w == 1) {
            #pragma unroll
            for (int rs = 0; rs < 2; ++rs)
                #pragma unroll
                for (int c = 0; c < 4; ++c)
                    #pragma unroll
                    for (int r = 0; r < 4; ++r)
                        obuf[1][(16 * rs + quad * 4 + r) * 66 + 16 * c + cl] = accO[rs][c][r];
        }
    }
    __syncthreads();
    if (w == 0) {
        #pragma unroll
        for (int rs = 0; rs < 2; ++rs)
            #pragma unroll
            for (int c = 0; c < 4; ++c)
                #pragma unroll
                for (int r = 0; r < 4; ++r) {
                    float v = accO[rs][c][r] + obuf[1][(16 * rs + quad * 4 + r) * 66 + 16 * c + cl];
                    int row = 16 * rs + quad * 4 + r;
                    out[(rowbase + row) * DK + 16 * c + cl] = v / lg[rs][r];
                }
    }
}

// ---------------------------------------------------------------------------
// k_dotse: edge dots only. grid (8,18) x 256.
// ---------------------------------------------------------------------------
__global__ __launch_bounds__(256) void k_dotse(
    const f16* __restrict__ qsp, const f16* __restrict__ ksp,
    float* __restrict__ De32)
{
    const int bx = blockIdx.x + 64, by = blockIdx.y;
    int ex = bx - 64;
    int b = ex >> 1;
    int half = ex & 1;
    if (half == 0 && by > 0) return;
    size_t qrow0 = (size_t)b * L_ + (half ? 2176 : 0);
    const int col0 = by * 128;
    const size_t krow0 = (size_t)b * L_ + col0;

    __shared__ f16 Qs[128 * 136];
    __shared__ f16 Ks[128 * 136];
    const int tid = threadIdx.x;

    #pragma unroll
    for (int i = 0; i < 8; ++i) {
        int g = tid + 256 * i;
        int r = g >> 4, c = g & 15;
        *(uint4*)(Qs + r * 136 + c * 8) = *(const uint4*)(qsp + (qrow0 + r) * 128 + c * 8);
        *(uint4*)(Ks + r * 136 + c * 8) = *(const uint4*)(ksp + (krow0 + r) * 128 + c * 8);
    }
    __syncthreads();

    const int w = tid >> 6, lane = tid & 63;
    const int cl = lane & 15, quad = lane >> 4;

    f32x4 acc[2][8];
    #pragma unroll
    for (int i = 0; i < 2; ++i)
        #pragma unroll
        for (int j = 0; j < 8; ++j) acc[i][j] = 0.f;

    #pragma unroll
    for (int h = 0; h < 2; ++h) {
        half8 ah[2], al[2];
        #pragma unroll
        for (int rs = 0; rs < 2; ++rs) {
            const f16* base = Qs + (32 * w + 16 * rs + cl) * 136 + h * 32 + quad * 8;
            ah[rs] = *(const half8*)(base);
            al[rs] = *(const half8*)(base + 64);
        }
        #pragma unroll
        for (int cq = 0; cq < 2; ++cq) {
            half8 bh[4], bl[4];
            #pragma unroll
            for (int cc = 0; cc < 4; ++cc) {
                const f16* base = Ks + (16 * (cq * 4 + cc) + cl) * 136 + h * 32 + quad * 8;
                bh[cc] = *(const half8*)(base);
                bl[cc] = *(const half8*)(base + 64);
            }
            #pragma unroll
            for (int rs = 0; rs < 2; ++rs)
                #pragma unroll
                for (int cc = 0; cc < 4; ++cc) {
                    int c = cq * 4 + cc;
                    acc[rs][c] = __builtin_amdgcn_mfma_f32_16x16x32_f16(ah[rs], bh[cc], acc[rs][c], 0, 0, 0);
                    acc[rs][c] = __builtin_amdgcn_mfma_f32_16x16x32_f16(ah[rs], bl[cc], acc[rs][c], 0, 0, 0);
                    acc[rs][c] = __builtin_amdgcn_mfma_f32_16x16x32_f16(al[rs], bh[cc], acc[rs][c], 0, 0, 0);
                }
        }
    }

    const int er0 = (bx - 64) * 128;
    #pragma unroll
    for (int rs = 0; rs < 2; ++rs)
        #pragma unroll
        for (int c = 0; c < 8; ++c)
            #pragma unroll
            for (int r = 0; r < 4; ++r) {
                int erow = er0 + 32 * w + 16 * rs + quad * 4 + r;
                int n    = col0 + 16 * c + cl;
                De32[(size_t)erow * LE + n] = acc[rs][c][r];
            }
}

// ---------------------------------------------------------------------------
// k_scane: edge softmax. grid 1024 x 256.
// ---------------------------------------------------------------------------
__global__ __launch_bounds__(256) void k_scane(
    const float* __restrict__ De32, f16* __restrict__ Dep)
{
    __shared__ float wmax[4], wsum[4];
    const int tid = threadIdx.x;
    const int er  = blockIdx.x;
    const int lane = tid & 63, wid = tid >> 6;
    const int r  = er & 255;
    const int Q  = (r < 128) ? r : (2048 + r);
    const float* Er32 = De32 + (size_t)er * LE;
    f16* Er = Dep + (size_t)er * LE;

    float v[9];
    #pragma unroll
    for (int i = 0; i < 9; ++i) {
        int j = tid + 256 * i;
        float d = Er32[j];
        v[i] = (j <= Q) ? d * SCALE : NEGINF;
    }
    float mx = v[0];
    #pragma unroll
    for (int i = 1; i < 9; ++i) mx = fmaxf(mx, v[i]);
    #pragma unroll
    for (int off = 1; off < 64; off <<= 1) mx = fmaxf(mx, __shfl_xor(mx, off));
    if (lane == 0) wmax[wid] = mx;
    __syncthreads();
    mx = fmaxf(fmaxf(wmax[0], wmax[1]), fmaxf(wmax[2], wmax[3]));

    float lsum = 0.f;
    #pragma unroll
    for (int i = 0; i < 9; ++i) {
        v[i] = __expf(v[i] - mx);
        lsum += v[i];
    }
    #pragma unroll
    for (int off = 1; off < 64; off <<= 1) lsum += __shfl_xor(lsum, off);
    if (lane == 0) wsum[wid] = lsum;
    __syncthreads();
    float inv = 1.f / (wsum[0] + wsum[1] + wsum[2] + wsum[3]);

    #pragma unroll
    for (int i = 0; i < 9; ++i)
        Er[tid + 256 * i] = (f16)(v[i] * inv);
}

// ---------------------------------------------------------------------------
// k_pve: edge PV. grid (16, 4) x 256.
// ---------------------------------------------------------------------------
__global__ __launch_bounds__(256) void k_pve(
    const f16* __restrict__ Pedge, const f16* __restrict__ vhT,
    float* __restrict__ Oe)
{
    __shared__ f16 Ps[64 * 72];
    __shared__ f16 Vt[64 * 72];
    const int tid = threadIdx.x;
    const int ks  = blockIdx.y;

    int row0 = blockIdx.x * 64;
    int b = row0 >> 8;
    int r0 = row0 & 255;
    const f16* Pb = Pedge;
    const size_t pitch = LE;
    int Qmax = (r0 < 128) ? (r0 + 63) : (2048 + r0 + 63);
    int cmax = Qmax >> 6;
    float* outp = Oe + (size_t)ks * NEDGE * DK;

    const int c_beg = ks * 9;
    int c_end = c_beg + 9;
    if (c_end > 36) c_end = 36;
    if (c_end > cmax + 1) c_end = cmax + 1;

    const int w = tid >> 6, lane = tid & 63;
    const int cl = lane & 15, quad = lane >> 4;
    f32x4 acc[4];
    #pragma unroll
    for (int c = 0; c < 4; ++c) acc[c] = 0.f;

    for (int ch = c_beg; ch < c_end; ++ch) {
        __syncthreads();
        #pragma unroll
        for (int i = 0; i < 2; ++i) {
            int g = tid + 256 * i;
            int r = g >> 3, c = g & 7;
            *(uint4*)(Ps + r * 72 + c * 8) =
                *(const uint4*)(Pb + (size_t)(row0 + r) * pitch + ch * 64 + c * 8);
            *(uint4*)(Vt + r * 72 + c * 8) =
                *(const uint4*)(vhT + (size_t)(b * 64 + r) * L_ + ch * 64 + c * 8);
        }
        __syncthreads();
        #pragma unroll
        for (int h = 0; h < 2; ++h) {
            half8 a = *(const half8*)(Ps + (16 * w + cl) * 72 + h * 32 + quad * 8);
            #pragma unroll
            for (int c = 0; c < 4; ++c) {
                half8 bv = *(const half8*)(Vt + (16 * c + cl) * 72 + h * 32 + quad * 8);
                acc[c] = __builtin_amdgcn_mfma_f32_16x16x32_f16(a, bv, acc[c], 0, 0, 0);
            }
        }
    }
    #pragma unroll
    for (int c = 0; c < 4; ++c)
        #pragma unroll
        for (int r = 0; r < 4; ++r) {
            int mrow = row0 + 16 * w + quad * 4 + r;
            int n    = 16 * c + cl;
            outp[(size_t)mrow * DK + n] = acc[c][r];
        }
}

// ---------------------------------------------------------------------------
// k_mergee: sum 4 edge partials. grid 256 x 256.
// ---------------------------------------------------------------------------
__global__ __launch_bounds__(256) void k_mergee(
    const float* __restrict__ Oe, float* __restrict__ out)
{
    const int e2 = blockIdx.x * 256 + threadIdx.x;
    const int er = e2 >> 6, c = e2 & 63;
    const int b  = er >> 8, r = er & 255;
    const int gQ = (r < 128) ? r : (2048 + r);
    const int NP = NEDGE * DK;
    float s = Oe[e2] + Oe[e2 + NP] + Oe[e2 + 2 * NP] + Oe[e2 + 3 * NP];
    out[((size_t)b * L_ + gQ) * DK + c] = s;
}

// ---------------------------------------------------------------------------
extern "C" void kernel_launch(void* const* d_in, const int* in_sizes, int n_in,
                              void* d_out, int out_size, void* d_ws, size_t ws_size,
                              hipStream_t stream)
{
    const float* x    = (const float*)d_in[0];
    const float* Wq   = (const float*)d_in[1];
    const float* Wk   = (const float*)d_in[2];
    const float* Wv   = (const float*)d_in[3];
    const float* Wqs  = (const float*)d_in[4];
    const float* Wks  = (const float*)d_in[5];
    const float* Wvs  = (const float*)d_in[6];
    const float* Wqe  = (const float*)d_in[7];
    const float* Wke  = (const float*)d_in[8];
    const float* Wve  = (const float*)d_in[9];
    const float* g0   = (const float*)d_in[10];
    const float* b0   = (const float*)d_in[11];
    const float* gs   = (const float*)d_in[12];
    const float* bs   = (const float*)d_in[13];
    const float* ge   = (const float*)d_in[14];
    const float* be   = (const float*)d_in[15];
    const float* cope = (const float*)d_in[16];

    const size_t NR = (size_t)B_ * L_;                 // 9216 rows
    f16*   qsp    = (f16*)d_ws;                        // NR*128
    f16*   ksp    = qsp + NR * 128;                    // NR*128
    f16*   vhT    = ksp + NR * 128;                    // NR*64
    f16*   Wsp    = vhT + NR * 64;                     // 9*65536
    f16*   copesp = Wsp + (size_t)9 * 65536;           // 128*128
    float* De32   = (float*)(copesp + 16384);          // NEDGE*LE f32
    float* Oe     = De32 + (size_t)NEDGE * LE;         // 4*NEDGE*64 f32
    f16*   Dep    = (f16*)(Oe + (size_t)4 * NEDGE * DK); // NEDGE*LE f16
    float* out    = (float*)d_out;

    k_wsplit<<<dim3(8, 10), 256, 0, stream>>>(Wq, Wk, Wv, Wqs, Wks, Wvs,
                                              Wqe, Wke, Wve, cope, Wsp, copesp);
    k_proj<<<288, 256, 0, stream>>>(x, Wsp, g0, b0, gs, bs, ge, be,
                                    qsp, ksp, vhT);
    k_dotse<<<dim3(8, 18), 256, 0, stream>>>(qsp, ksp, De32);
    k_fmid<<<256, 512, 0, stream>>>(qsp, ksp, vhT, copesp, out);
    k_scane<<<NEDGE, 256, 0, stream>>>(De32, Dep);
    k_pve<<<dim3(16, 4), 256, 0, stream>>>(Dep, vhT, Oe);
    k_mergee<<<256, 256, 0, stream>>>(Oe, out);
}

// Round 5
// 229.138 us; speedup vs baseline: 1.0799x; 1.0799x over previous
//
#include <hip/hip_runtime.h>
#include <math.h>

#define B_    4
#define SEQ_  2048
#define S_    128
#define L_    2304          // SEQ + 2*S
#define DIN   512
#define DK    64
#define NEGINF (-1e30f)
#define SCALE 0.125f
#define NCOLS 2176          // start(128) + mid(2048) key columns in D
#define NMID  8192          // B_*SEQ_
#define NEDGE 1024          // B_*2*S_
#define LE    2304          // edge De row length

typedef _Float16 f16;
typedef __attribute__((ext_vector_type(8))) _Float16 half8;
typedef __attribute__((ext_vector_type(4))) float f32x4;

union U4 { uint4 u; f16 h[8]; half8 v; };

// ---------------------------------------------------------------------------
// k_wsplit: pre-split all 9 W matrices (512x64 f32) into fp16 hi/lo,
// transposed layout Wsp[mat][col][k: hi 0..511 | lo 512..1023].
// grid (8, 9) x 256.
// ---------------------------------------------------------------------------
__global__ __launch_bounds__(256) void k_wsplit(
    const float* __restrict__ Wq,  const float* __restrict__ Wk,  const float* __restrict__ Wv,
    const float* __restrict__ Wqs, const float* __restrict__ Wks, const float* __restrict__ Wvs,
    const float* __restrict__ Wqe, const float* __restrict__ Wke, const float* __restrict__ Wve,
    f16* __restrict__ Wsp)
{
    __shared__ float xs[64 * 68];
    const int kt  = blockIdx.x;
    const int mat = blockIdx.y;
    const float* W;
    switch (mat) {
        case 0: W = Wq;  break; case 1: W = Wk;  break; case 2: W = Wv;  break;
        case 3: W = Wqs; break; case 4: W = Wks; break; case 5: W = Wvs; break;
        case 6: W = Wqe; break; case 7: W = Wke; break; default: W = Wve; break;
    }
    const int tid = threadIdx.x;
    const int k0  = kt * 64;
    #pragma unroll
    for (int i = 0; i < 4; ++i) {
        int g = tid + 256 * i;
        int k = g >> 4, c4 = g & 15;
        *(float4*)(xs + k * 68 + c4 * 4) = ((const float4*)W)[(size_t)(k0 + k) * 16 + c4];
    }
    __syncthreads();
    const int col = tid & 63, hf = tid >> 6;
    const int kk0 = hf * 16;
    U4 hi0, hi1, lo0, lo1;
    #pragma unroll
    for (int j = 0; j < 8; ++j) {
        float v0 = xs[(kk0 + j) * 68 + col];
        float v1 = xs[(kk0 + 8 + j) * 68 + col];
        hi0.h[j] = (f16)v0; lo0.h[j] = (f16)(v0 - (float)hi0.h[j]);
        hi1.h[j] = (f16)v1; lo1.h[j] = (f16)(v1 - (float)hi1.h[j]);
    }
    f16* dst = Wsp + (size_t)mat * 65536 + (size_t)col * 1024 + k0 + kk0;
    *(uint4*)(dst)       = hi0.u;
    *(uint4*)(dst + 8)   = hi1.u;
    *(uint4*)(dst + 512) = lo0.u;
    *(uint4*)(dst + 520) = lo1.u;
}

// ---------------------------------------------------------------------------
// k_proj: fused LayerNorm + all three projections. grid 288 x 256.
// A-fragments computed in-register (no As LDS): 52KB LDS -> 3 blocks/CU.
// ---------------------------------------------------------------------------
__global__ __launch_bounds__(256) void k_proj(
    const float* __restrict__ x, const f16* __restrict__ Wsp,
    const float* __restrict__ g0, const float* __restrict__ b0,
    const float* __restrict__ gs, const float* __restrict__ bs,
    const float* __restrict__ ge, const float* __restrict__ be,
    f16* __restrict__ qsp, f16* __restrict__ ksp, f16* __restrict__ vhT)
{
    __shared__ f16 Bs[3 * 64 * 136];   // per-mat [col][hi|lo|pad]
    __shared__ float mean_s[32], rstd_s[32];
    const int tid  = threadIdx.x;
    const int row0 = blockIdx.x * 32;
    const int rseq = row0 % L_;
    const int seg  = (rseq < S_) ? 0 : (rseq >= L_ - S_) ? 2 : 1;
    const int mat0 = (seg == 0) ? 3 : (seg == 2) ? 6 : 0;
    const float* gg = (seg == 0) ? gs : (seg == 2) ? ge : g0;
    const float* bb = (seg == 0) ? bs : (seg == 2) ? be : b0;

    // row stats: 8 threads per row, 64 elems each
    {
        const int rr = tid >> 3, qq = tid & 7;
        const float4* xr = (const float4*)(x + (size_t)(row0 + rr) * DIN) + qq * 16;
        float s = 0.f, s2 = 0.f;
        #pragma unroll
        for (int i = 0; i < 16; ++i) {
            float4 v = xr[i];
            s  += v.x + v.y + v.z + v.w;
            s2 += v.x * v.x + v.y * v.y + v.z * v.z + v.w * v.w;
        }
        s  += __shfl_xor(s, 1);  s  += __shfl_xor(s, 2);  s  += __shfl_xor(s, 4);
        s2 += __shfl_xor(s2, 1); s2 += __shfl_xor(s2, 2); s2 += __shfl_xor(s2, 4);
        if (qq == 0) {
            float mean = s * (1.f / DIN);
            mean_s[rr] = mean;
            rstd_s[rr] = rsqrtf(s2 * (1.f / DIN) - mean * mean + 1e-5f);
        }
    }

    const int w = tid >> 6, lane = tid & 63;
    const int cl = lane & 15, quad = lane >> 4;
    const int r0 = 16 * (w >> 1), c0 = 32 * (w & 1);   // wave: 16 rows x 32 cols

    f32x4 acc[3][2];
    #pragma unroll
    for (int m = 0; m < 3; ++m)
        #pragma unroll
        for (int j = 0; j < 2; ++j) acc[m][j] = 0.f;

    const int arow = row0 + r0 + cl;

    for (int kc = 0; kc < DIN; kc += 64) {
        __syncthreads();
        // stage B for all 3 mats: 3 x 64 cols x 8 groups = 1536 units
        #pragma unroll
        for (int i = 0; i < 6; ++i) {
            int g = tid + 256 * i;
            int mm = g >> 9, rem = g & 511;
            int col = rem >> 3, c8 = rem & 7;
            const f16* src = Wsp + (size_t)(mat0 + mm) * 65536 + (size_t)col * 1024 + kc + c8 * 8;
            f16* dst = Bs + mm * 8704 + col * 136 + c8 * 8;
            *(uint4*)(dst)      = *(const uint4*)(src);
            *(uint4*)(dst + 64) = *(const uint4*)(src + 512);
        }
        __syncthreads();
        const float mean = mean_s[r0 + cl], rstd = rstd_s[r0 + cl];
        #pragma unroll
        for (int h = 0; h < 2; ++h) {
            // in-register LN'd A fragment (hi/lo split)
            const float* xp = x + (size_t)arow * DIN + kc + h * 32 + quad * 8;
            float4 a0 = *(const float4*)xp;
            float4 a1 = *(const float4*)(xp + 4);
            const float* gp = gg + kc + h * 32 + quad * 8;
            const float* bp = bb + kc + h * 32 + quad * 8;
            float4 gA = *(const float4*)gp, gB = *(const float4*)(gp + 4);
            float4 bA = *(const float4*)bp, bB = *(const float4*)(bp + 4);
            float n[8];
            n[0] = (a0.x - mean) * rstd * gA.x + bA.x;
            n[1] = (a0.y - mean) * rstd * gA.y + bA.y;
            n[2] = (a0.z - mean) * rstd * gA.z + bA.z;
            n[3] = (a0.w - mean) * rstd * gA.w + bA.w;
            n[4] = (a1.x - mean) * rstd * gB.x + bB.x;
            n[5] = (a1.y - mean) * rstd * gB.y + bB.y;
            n[6] = (a1.z - mean) * rstd * gB.z + bB.z;
            n[7] = (a1.w - mean) * rstd * gB.w + bB.w;
            U4 hi, lo;
            #pragma unroll
            for (int j = 0; j < 8; ++j) {
                hi.h[j] = (f16)n[j];
                lo.h[j] = (f16)(n[j] - (float)hi.h[j]);
            }
            half8 ah = hi.v, al = lo.v;
            #pragma unroll
            for (int m = 0; m < 3; ++m)
                #pragma unroll
                for (int cs = 0; cs < 2; ++cs) {
                    const f16* base = Bs + m * 8704 + (c0 + 16 * cs + cl) * 136 + h * 32 + quad * 8;
                    half8 bh = *(const half8*)(base);
                    half8 bl = *(const half8*)(base + 64);
                    acc[m][cs] = __builtin_amdgcn_mfma_f32_16x16x32_f16(ah, bh, acc[m][cs], 0, 0, 0);
                    acc[m][cs] = __builtin_amdgcn_mfma_f32_16x16x32_f16(ah, bl, acc[m][cs], 0, 0, 0);
                    acc[m][cs] = __builtin_amdgcn_mfma_f32_16x16x32_f16(al, bh, acc[m][cs], 0, 0, 0);
                }
        }
    }

    const int bI = row0 / L_;
    const int rb = row0 - bI * L_;
    #pragma unroll
    for (int m = 0; m < 3; ++m) {
        f16* sp = (m == 0) ? qsp : ksp;
        #pragma unroll
        for (int cs = 0; cs < 2; ++cs)
            #pragma unroll
            for (int r = 0; r < 4; ++r) {
                int lrow = r0 + quad * 4 + r;
                int col  = c0 + 16 * cs + cl;
                float v  = acc[m][cs][r];
                size_t grow = (size_t)(row0 + lrow);
                if (m < 2) {
                    f16 hv = (f16)v;
                    sp[grow * 128 + col]      = hv;
                    sp[grow * 128 + 64 + col] = (f16)(v - (float)hv);
                } else {
                    vhT[(size_t)(bI * 64 + col) * L_ + rb + lrow] = (f16)v;
                }
            }
    }
}

// ---------------------------------------------------------------------------
// k_dots: mid + edge dots via split-fp16 MFMA; 128x128 tiles; fp32 D/De.
// Q fragments direct from L2 (no Qs LDS): 34.8KB LDS -> 4 blocks/CU.
// grid (72,18) x 256.
// ---------------------------------------------------------------------------
__global__ __launch_bounds__(256, 3) void k_dots(
    const f16* __restrict__ qsp, const f16* __restrict__ ksp,
    float* __restrict__ D32, float* __restrict__ G, float* __restrict__ De32)
{
    const int bx = blockIdx.x, by = blockIdx.y;
    const bool edge = (bx >= 64);
    int b, q0 = 0;
    size_t qrow0;
    if (!edge) {
        if (by >= 17) return;                 // NCOLS = 17 * 128
        b = bx >> 4;
        q0 = (bx * 128) & 2047;
        qrow0 = (size_t)b * L_ + S_ + q0;
    } else {
        int ex = bx - 64;
        b = ex >> 1;
        int half = ex & 1;
        if (half == 0 && by > 0) return;      // start rows see only cols <128
        qrow0 = (size_t)b * L_ + (half ? 2176 : 0);
    }
    const int col0 = by * 128;
    const size_t krow0 = (size_t)b * L_ + col0;

    __shared__ f16 Ks[128 * 136];
    const int tid = threadIdx.x;
    const int w = tid >> 6, lane = tid & 63;
    const int cl = lane & 15, quad = lane >> 4;

    // Q fragments direct from global (L2-resident qsp)
    half8 qh[2][2], qlo[2][2];
    #pragma unroll
    for (int rs = 0; rs < 2; ++rs)
        #pragma unroll
        for (int h = 0; h < 2; ++h) {
            const f16* qp = qsp + (qrow0 + 32 * w + 16 * rs + cl) * 128 + h * 32 + quad * 8;
            qh[rs][h]  = *(const half8*)qp;
            qlo[rs][h] = *(const half8*)(qp + 64);
        }

    #pragma unroll
    for (int i = 0; i < 8; ++i) {
        int g = tid + 256 * i;
        int r = g >> 4, c = g & 15;
        *(uint4*)(Ks + r * 136 + c * 8) = *(const uint4*)(ksp + (krow0 + r) * 128 + c * 8);
    }
    __syncthreads();

    f32x4 acc[2][8];
    #pragma unroll
    for (int i = 0; i < 2; ++i)
        #pragma unroll
        for (int j = 0; j < 8; ++j) acc[i][j] = 0.f;

    #pragma unroll
    for (int h = 0; h < 2; ++h) {
        #pragma unroll
        for (int cq = 0; cq < 2; ++cq) {
            half8 bh[4], bl[4];
            #pragma unroll
            for (int cc = 0; cc < 4; ++cc) {
                const f16* base = Ks + (16 * (cq * 4 + cc) + cl) * 136 + h * 32 + quad * 8;
                bh[cc] = *(const half8*)(base);
                bl[cc] = *(const half8*)(base + 64);
            }
            #pragma unroll
            for (int rs = 0; rs < 2; ++rs)
                #pragma unroll
                for (int cc = 0; cc < 4; ++cc) {
                    int c = cq * 4 + cc;
                    acc[rs][c] = __builtin_amdgcn_mfma_f32_16x16x32_f16(qh[rs][h], bh[cc], acc[rs][c], 0, 0, 0);
                    acc[rs][c] = __builtin_amdgcn_mfma_f32_16x16x32_f16(qh[rs][h], bl[cc], acc[rs][c], 0, 0, 0);
                    acc[rs][c] = __builtin_amdgcn_mfma_f32_16x16x32_f16(qlo[rs][h], bh[cc], acc[rs][c], 0, 0, 0);
                }
        }
    }

    if (!edge) {
        const int gr0 = bx * 128;
        const bool writeD = (by == 0) || ((by - 1) <= (q0 >> 7));
        if (writeD) {
            #pragma unroll
            for (int rs = 0; rs < 2; ++rs)
                #pragma unroll
                for (int c = 0; c < 8; ++c)
                    #pragma unroll
                    for (int r = 0; r < 4; ++r) {
                        int mrow = gr0 + 32 * w + 16 * rs + quad * 4 + r;
                        int n    = col0 + 16 * c + cl;
                        D32[(size_t)mrow * NCOLS + n] = acc[rs][c][r];
                    }
        }
        if (by >= 1) {
            const int chm = 2 * (by - 1);
            #pragma unroll
            for (int rs = 0; rs < 2; ++rs)
                #pragma unroll
                for (int r = 0; r < 4; ++r) {
                    float sA = 0.f, sB = 0.f;
                    #pragma unroll
                    for (int cc = 0; cc < 4; ++cc) {
                        sA += 1.f / (1.f + __expf(-acc[rs][cc][r]));
                        sB += 1.f / (1.f + __expf(-acc[rs][4 + cc][r]));
                    }
                    #pragma unroll
                    for (int off = 1; off < 16; off <<= 1) {
                        sA += __shfl_xor(sA, off);
                        sB += __shfl_xor(sB, off);
                    }
                    if (cl == 0) {
                        int row = gr0 + 32 * w + 16 * rs + quad * 4 + r;
                        G[(size_t)row * 32 + chm]     = sA;
                        G[(size_t)row * 32 + chm + 1] = sB;
                    }
                }
        }
    } else {
        const int er0 = (bx - 64) * 128;
        #pragma unroll
        for (int rs = 0; rs < 2; ++rs)
            #pragma unroll
            for (int c = 0; c < 8; ++c)
                #pragma unroll
                for (int r = 0; r < 4; ++r) {
                    int erow = er0 + 32 * w + 16 * rs + quad * 4 + r;
                    int n    = col0 + 16 * c + cl;
                    De32[(size_t)erow * LE + n] = acc[rs][c][r];
                }
    }
}

// ---------------------------------------------------------------------------
// k_scan: grid 9216 x 256. Reads exact fp32 dots; writes fp16 P.
// ---------------------------------------------------------------------------
__global__ __launch_bounds__(256) void k_scan(
    const f16* __restrict__ qsp, const float* __restrict__ cope,
    const float* __restrict__ G,
    const float* __restrict__ D32, f16* __restrict__ Dp,
    const float* __restrict__ De32, f16* __restrict__ Dep)
{
    __shared__ f16   qvh[128];
    __shared__ float li[128];
    __shared__ float Gs[32];
    __shared__ float Gsf[32];
    __shared__ float wmax[4], wsum[4];
    const int tid = threadIdx.x;
    const int gr  = blockIdx.x;
    const int lane = tid & 63, wid = tid >> 6;

    if (gr < NMID) {
        const int b = gr >> 11;
        const int q = gr & 2047;
        const size_t grow = (size_t)b * L_ + S_ + q;
        const int qlim = (q & ~63) + 64;

        if (tid < 16) ((uint4*)qvh)[tid] = ((const uint4*)(qsp + grow * 128))[tid];
        if (tid >= 16 && tid < 24)
            ((float4*)Gs)[tid - 16] = ((const float4*)G)[(size_t)gr * 8 + tid - 16];
        __syncthreads();
        if (tid < 128) {
            float a = 0.f;
            #pragma unroll
            for (int d = 0; d < DK; ++d)
                a += ((float)qvh[d] + (float)qvh[64 + d]) * cope[d * S_ + tid];
            li[tid] = a;
        }
        if (tid >= 128 && tid < 160) {
            int c = tid - 128;
            float s = 0.f;
            for (int cc = c + 1; cc < 32; ++cc) s += Gs[cc];
            Gsf[c] = s;
        }

        const float* Sr = D32 + (size_t)gr * NCOLS;
        f16* Dr = Dp + (size_t)gr * NCOLS;
        const int j0 = tid * 8;
        const int cg = tid >> 3, sl = tid & 7;
        float dot[8], gte[8];
        float csum = 0.f;
        if (j0 < qlim) {
            float4 t0 = *(const float4*)(Sr + 128 + j0);
            float4 t1 = *(const float4*)(Sr + 128 + j0 + 4);
            dot[0] = t0.x; dot[1] = t0.y; dot[2] = t0.z; dot[3] = t0.w;
            dot[4] = t1.x; dot[5] = t1.y; dot[6] = t1.z; dot[7] = t1.w;
            #pragma unroll
            for (int jj = 0; jj < 8; ++jj) {
                gte[jj] = 1.f / (1.f + __expf(-dot[jj]));
                csum += gte[jj];
            }
        } else {
            #pragma unroll
            for (int jj = 0; jj < 8; ++jj) { dot[jj] = 0.f; gte[jj] = 0.f; }
        }
        float sv = (tid < 128) ? Sr[tid] * SCALE : NEGINF;

        float inc = csum;
        #pragma unroll
        for (int off = 1; off < 8; off <<= 1) {
            float u = __shfl_down(inc, off, 8);
            if (sl + off < 8) inc += u;
        }
        __syncthreads();
        float run = (inc - csum) + Gsf[cg];

        float p8[8];
        #pragma unroll
        for (int jj = 7; jj >= 0; --jj) {
            run += gte[jj];
            float pos = fminf(run, (float)(S_ - 1));
            float pfl = floorf(pos);
            int ic  = (int)ceilf(pos);
            int ifl = (int)pfl;
            float w = pos - pfl;
            float bias = li[ic] * w + li[ifl] * (1.f - w);
            p8[jj] = (j0 + jj <= q) ? dot[jj] * SCALE + bias : NEGINF;
        }

        float mx = sv;
        #pragma unroll
        for (int jj = 0; jj < 8; ++jj) mx = fmaxf(mx, p8[jj]);
        #pragma unroll
        for (int off = 1; off < 64; off <<= 1) mx = fmaxf(mx, __shfl_xor(mx, off));
        if (lane == 0) wmax[wid] = mx;
        __syncthreads();
        mx = fmaxf(fmaxf(wmax[0], wmax[1]), fmaxf(wmax[2], wmax[3]));

        float lsum = 0.f;
        float e8[8];
        #pragma unroll
        for (int jj = 0; jj < 8; ++jj) {
            e8[jj] = __expf(p8[jj] - mx);
            lsum += e8[jj];
        }
        float es = 0.f;
        if (tid < 128) { es = __expf(sv - mx); lsum += es; }
        #pragma unroll
        for (int off = 1; off < 64; off <<= 1) lsum += __shfl_xor(lsum, off);
        if (lane == 0) wsum[wid] = lsum;
        __syncthreads();
        float inv = 1.f / (wsum[0] + wsum[1] + wsum[2] + wsum[3]);

        if (j0 < qlim) {
            U4 o;
            #pragma unroll
            for (int jj = 0; jj < 8; ++jj) o.h[jj] = (f16)(e8[jj] * inv);
            *(uint4*)(Dr + 128 + j0) = o.u;
        }
        if (tid < 128) Dr[tid] = (f16)(es * inv);
    } else {
        const int er = gr - NMID;
        const int r  = er & 255;
        const int Q  = (r < 128) ? r : (2048 + r);
        const float* Er32 = De32 + (size_t)er * LE;
        f16* Er = Dep + (size_t)er * LE;

        float v[9];
        #pragma unroll
        for (int i = 0; i < 9; ++i) {
            int j = tid + 256 * i;
            float d = Er32[j];
            v[i] = (j <= Q) ? d * SCALE : NEGINF;
        }
        float mx = v[0];
        #pragma unroll
        for (int i = 1; i < 9; ++i) mx = fmaxf(mx, v[i]);
        #pragma unroll
        for (int off = 1; off < 64; off <<= 1) mx = fmaxf(mx, __shfl_xor(mx, off));
        if (lane == 0) wmax[wid] = mx;
        __syncthreads();
        mx = fmaxf(fmaxf(wmax[0], wmax[1]), fmaxf(wmax[2], wmax[3]));

        float lsum = 0.f;
        #pragma unroll
        for (int i = 0; i < 9; ++i) {
            v[i] = __expf(v[i] - mx);
            lsum += v[i];
        }
        #pragma unroll
        for (int off = 1; off < 64; off <<= 1) lsum += __shfl_xor(lsum, off);
        if (lane == 0) wsum[wid] = lsum;
        __syncthreads();
        float inv = 1.f / (wsum[0] + wsum[1] + wsum[2] + wsum[3]);

        #pragma unroll
        for (int i = 0; i < 9; ++i)
            Er[tid + 256 * i] = (f16)(v[i] * inv);
    }
}

// ---------------------------------------------------------------------------
// k_pv: mid + edge PV, barrier-free main loop, in-block 4-way chunk split +
// merge; writes out directly. grid 288 x 512 (bx<256: mid 32-row strips;
// bx>=256: edge 32-row strips). P/V fragments direct from L2.
// ---------------------------------------------------------------------------
__global__ __launch_bounds__(512) void k_pv(
    const f16* __restrict__ Pmid, const f16* __restrict__ Pedge,
    const f16* __restrict__ vhT, float* __restrict__ out)
{
    __shared__ float mbuf[3][2][16 * 68];
    const int tid = threadIdx.x, bx = blockIdx.x;
    const int w = tid >> 6, lane = tid & 63;
    const int cl = lane & 15, quad = lane >> 4;
    const int g = w >> 2, ql = w & 3;
    const bool edge = (bx >= 256);

    const f16* Pb;
    size_t prow0, pitch;
    int b, cmax, cap, q0 = 0, r0 = 0;
    if (!edge) {
        int gr0 = bx * 32;
        b = gr0 >> 11; q0 = gr0 & 2047;
        Pb = Pmid; prow0 = gr0; pitch = NCOLS; cap = 34;
        cmax = (159 + q0) >> 6;
    } else {
        int er0 = (bx - 256) * 32;
        b = er0 >> 8; r0 = er0 & 255;
        Pb = Pedge; prow0 = er0; pitch = LE; cap = 36;
        int Qmax = (r0 < 128) ? (r0 + 31) : (2048 + r0 + 31);
        cmax = Qmax >> 6;
    }
    int c_end = cmax + 1;
    if (c_end > cap) c_end = cap;

    f32x4 acc[4];
    #pragma unroll
    for (int c = 0; c < 4; ++c) acc[c] = 0.f;

    for (int ch = ql; ch < c_end; ch += 4) {
        #pragma unroll
        for (int h = 0; h < 2; ++h) {
            half8 pa = *(const half8*)(Pb + (prow0 + 16 * g + cl) * pitch + ch * 64 + h * 32 + quad * 8);
            #pragma unroll
            for (int c2 = 0; c2 < 4; ++c2) {
                half8 bv = *(const half8*)(vhT + (size_t)(b * 64 + 16 * c2 + cl) * L_ + ch * 64 + h * 32 + quad * 8);
                acc[c2] = __builtin_amdgcn_mfma_f32_16x16x32_f16(pa, bv, acc[c2], 0, 0, 0);
            }
        }
    }

    if (ql != 0) {
        #pragma unroll
        for (int c2 = 0; c2 < 4; ++c2)
            #pragma unroll
            for (int r = 0; r < 4; ++r)
                mbuf[ql - 1][g][(quad * 4 + r) * 68 + 16 * c2 + cl] = acc[c2][r];
    }
    __syncthreads();
    if (ql == 0) {
        #pragma unroll
        for (int c2 = 0; c2 < 4; ++c2)
            #pragma unroll
            for (int r = 0; r < 4; ++r) {
                int idx = (quad * 4 + r) * 68 + 16 * c2 + cl;
                float v = acc[c2][r] + mbuf[0][g][idx] + mbuf[1][g][idx] + mbuf[2][g][idx];
                int lrow = 16 * g + quad * 4 + r;
                size_t grow;
                if (!edge) {
                    grow = (size_t)b * L_ + S_ + q0 + lrow;
                } else {
                    int rr = r0 + lrow;
                    int gQ = (rr < 128) ? rr : (2048 + rr);
                    grow = (size_t)b * L_ + gQ;
                }
                out[grow * DK + 16 * c2 + cl] = v;
            }
    }
}

// ---------------------------------------------------------------------------
extern "C" void kernel_launch(void* const* d_in, const int* in_sizes, int n_in,
                              void* d_out, int out_size, void* d_ws, size_t ws_size,
                              hipStream_t stream)
{
    const float* x    = (const float*)d_in[0];
    const float* Wq   = (const float*)d_in[1];
    const float* Wk   = (const float*)d_in[2];
    const float* Wv   = (const float*)d_in[3];
    const float* Wqs  = (const float*)d_in[4];
    const float* Wks  = (const float*)d_in[5];
    const float* Wvs  = (const float*)d_in[6];
    const float* Wqe  = (const float*)d_in[7];
    const float* Wke  = (const float*)d_in[8];
    const float* Wve  = (const float*)d_in[9];
    const float* g0   = (const float*)d_in[10];
    const float* b0   = (const float*)d_in[11];
    const float* gs   = (const float*)d_in[12];
    const float* bs   = (const float*)d_in[13];
    const float* ge   = (const float*)d_in[14];
    const float* be   = (const float*)d_in[15];
    const float* cope = (const float*)d_in[16];

    const size_t NR = (size_t)B_ * L_;               // 9216 rows
    f16*   qsp   = (f16*)d_ws;                       // NR*128 h (hi|lo)
    f16*   ksp   = qsp + NR * 128;                   // NR*128 h
    f16*   vhT   = ksp + NR * 128;                   // NR*64 h
    f16*   Wsp   = vhT + NR * 64;                    // 9*65536 h
    float* G     = (float*)(Wsp + (size_t)9 * 65536); // NMID*32 f32
    float* Dm32  = G + (size_t)NMID * 32;            // NMID*NCOLS f32 (raw dots)
    float* De32  = Dm32 + (size_t)NMID * NCOLS;      // NEDGE*LE f32 (raw dots)
    f16*   Dp    = (f16*)(De32 + (size_t)NEDGE * LE);// NMID*NCOLS h (P)
    f16*   Dep   = Dp + (size_t)NMID * NCOLS;        // NEDGE*LE h (P)
    float* out   = (float*)d_out;

    k_wsplit<<<dim3(8, 9), 256, 0, stream>>>(Wq, Wk, Wv, Wqs, Wks, Wvs,
                                             Wqe, Wke, Wve, Wsp);
    k_proj<<<288, 256, 0, stream>>>(x, Wsp, g0, b0, gs, bs, ge, be,
                                    qsp, ksp, vhT);
    k_dots<<<dim3(72, 18), 256, 0, stream>>>(qsp, ksp, Dm32, G, De32);
    k_scan<<<NMID + NEDGE, 256, 0, stream>>>(qsp, cope, G, Dm32, Dp, De32, Dep);
    k_pv<<<288, 512, 0, stream>>>(Dp, Dep, vhT, out);
}

// Round 6
// 225.063 us; speedup vs baseline: 1.0995x; 1.0181x over previous
//
#include <hip/hip_runtime.h>
#include <math.h>

#define B_    4
#define SEQ_  2048
#define S_    128
#define L_    2304          // SEQ + 2*S
#define DIN   512
#define DK    64
#define NEGINF (-1e30f)
#define SCALE 0.125f
#define NCOLS 2176          // start(128) + mid(2048) key columns in D
#define NMID  8192          // B_*SEQ_
#define NEDGE 1024          // B_*2*S_
#define LE    2304          // edge De row length

typedef _Float16 f16;
typedef __attribute__((ext_vector_type(8))) _Float16 half8;
typedef __attribute__((ext_vector_type(4))) float f32x4;

union U4 { uint4 u; f16 h[8]; half8 v; };

// ---------------------------------------------------------------------------
// k_wsplit: pre-split all 9 W matrices (512x64 f32) into fp16 hi/lo,
// transposed layout Wsp[mat][col][k: hi 0..511 | lo 512..1023].
// grid (8, 9) x 256.
// ---------------------------------------------------------------------------
__global__ __launch_bounds__(256) void k_wsplit(
    const float* __restrict__ Wq,  const float* __restrict__ Wk,  const float* __restrict__ Wv,
    const float* __restrict__ Wqs, const float* __restrict__ Wks, const float* __restrict__ Wvs,
    const float* __restrict__ Wqe, const float* __restrict__ Wke, const float* __restrict__ Wve,
    f16* __restrict__ Wsp)
{
    __shared__ float xs[64 * 68];
    const int kt  = blockIdx.x;
    const int mat = blockIdx.y;
    const float* W;
    switch (mat) {
        case 0: W = Wq;  break; case 1: W = Wk;  break; case 2: W = Wv;  break;
        case 3: W = Wqs; break; case 4: W = Wks; break; case 5: W = Wvs; break;
        case 6: W = Wqe; break; case 7: W = Wke; break; default: W = Wve; break;
    }
    const int tid = threadIdx.x;
    const int k0  = kt * 64;
    #pragma unroll
    for (int i = 0; i < 4; ++i) {
        int g = tid + 256 * i;
        int k = g >> 4, c4 = g & 15;
        *(float4*)(xs + k * 68 + c4 * 4) = ((const float4*)W)[(size_t)(k0 + k) * 16 + c4];
    }
    __syncthreads();
    const int col = tid & 63, hf = tid >> 6;
    const int kk0 = hf * 16;
    U4 hi0, hi1, lo0, lo1;
    #pragma unroll
    for (int j = 0; j < 8; ++j) {
        float v0 = xs[(kk0 + j) * 68 + col];
        float v1 = xs[(kk0 + 8 + j) * 68 + col];
        hi0.h[j] = (f16)v0; lo0.h[j] = (f16)(v0 - (float)hi0.h[j]);
        hi1.h[j] = (f16)v1; lo1.h[j] = (f16)(v1 - (float)hi1.h[j]);
    }
    f16* dst = Wsp + (size_t)mat * 65536 + (size_t)col * 1024 + k0 + kk0;
    *(uint4*)(dst)       = hi0.u;
    *(uint4*)(dst + 8)   = hi1.u;
    *(uint4*)(dst + 512) = lo0.u;
    *(uint4*)(dst + 520) = lo1.u;
}

// ---------------------------------------------------------------------------
// k_proj v3: latency-tolerant fused LayerNorm + q,k,v projections.
// grid 576 x 256: 16 rows per block. A tile (LN'd, hi/lo) staged ONCE in
// LDS (33KB, pitch 1032 -> uniform bank groups); k-loop has ZERO barriers:
// B fragments read straight from L2-resident Wsp, fully unrolled.
// Wave w covers 16 rows x 48 cols (3 16-col tiles across the 3 matrices).
// ---------------------------------------------------------------------------
__global__ __launch_bounds__(256) void k_proj(
    const float* __restrict__ x, const f16* __restrict__ Wsp,
    const float* __restrict__ g0, const float* __restrict__ b0,
    const float* __restrict__ gs, const float* __restrict__ bs,
    const float* __restrict__ ge, const float* __restrict__ be,
    f16* __restrict__ qsp, f16* __restrict__ ksp, f16* __restrict__ vhT)
{
    __shared__ f16 As[16 * 1032];      // [row][k: hi 0..511 | lo 512..1023 | pad]
    __shared__ float mean_s[16], rstd_s[16];
    const int tid  = threadIdx.x;
    const int row0 = blockIdx.x * 16;
    const int rseq = row0 % L_;
    const int seg  = (rseq < S_) ? 0 : (rseq >= L_ - S_) ? 2 : 1;
    const int mat0 = (seg == 0) ? 3 : (seg == 2) ? 6 : 0;
    const float* gg = (seg == 0) ? gs : (seg == 2) ? ge : g0;
    const float* bb = (seg == 0) ? bs : (seg == 2) ? be : b0;

    // row stats: 16 threads per row, 32 elems each
    {
        const int rr = tid >> 4, qq = tid & 15;
        const float4* xr = (const float4*)(x + (size_t)(row0 + rr) * DIN) + qq * 8;
        float s = 0.f, s2 = 0.f;
        #pragma unroll
        for (int i = 0; i < 8; ++i) {
            float4 v = xr[i];
            s  += v.x + v.y + v.z + v.w;
            s2 += v.x * v.x + v.y * v.y + v.z * v.z + v.w * v.w;
        }
        s  += __shfl_xor(s, 1);  s  += __shfl_xor(s, 2);
        s  += __shfl_xor(s, 4);  s  += __shfl_xor(s, 8);
        s2 += __shfl_xor(s2, 1); s2 += __shfl_xor(s2, 2);
        s2 += __shfl_xor(s2, 4); s2 += __shfl_xor(s2, 8);
        if (qq == 0) {
            float mean = s * (1.f / DIN);
            mean_s[rr] = mean;
            rstd_s[rr] = rsqrtf(s2 * (1.f / DIN) - mean * mean + 1e-5f);
        }
    }
    __syncthreads();

    // stage full LN'd A tile once (hi/lo split)
    {
        const int r = tid >> 4, c32 = (tid & 15) * 32;
        const float mean = mean_s[r], rstd = rstd_s[r];
        f16* dst = As + r * 1032 + c32;
        #pragma unroll
        for (int i = 0; i < 4; ++i) {
            const float* xp = x + (size_t)(row0 + r) * DIN + c32 + i * 8;
            float4 a0 = *(const float4*)xp;
            float4 a1 = *(const float4*)(xp + 4);
            const float* gp = gg + c32 + i * 8;
            const float* bp = bb + c32 + i * 8;
            float4 gA = *(const float4*)gp, gB = *(const float4*)(gp + 4);
            float4 bA = *(const float4*)bp, bB = *(const float4*)(bp + 4);
            float n[8];
            n[0] = (a0.x - mean) * rstd * gA.x + bA.x;
            n[1] = (a0.y - mean) * rstd * gA.y + bA.y;
            n[2] = (a0.z - mean) * rstd * gA.z + bA.z;
            n[3] = (a0.w - mean) * rstd * gA.w + bA.w;
            n[4] = (a1.x - mean) * rstd * gB.x + bB.x;
            n[5] = (a1.y - mean) * rstd * gB.y + bB.y;
            n[6] = (a1.z - mean) * rstd * gB.z + bB.z;
            n[7] = (a1.w - mean) * rstd * gB.w + bB.w;
            U4 hi, lo;
            #pragma unroll
            for (int j = 0; j < 8; ++j) {
                hi.h[j] = (f16)n[j];
                lo.h[j] = (f16)(n[j] - (float)hi.h[j]);
            }
            *(uint4*)(dst + i * 8)       = hi.u;
            *(uint4*)(dst + 512 + i * 8) = lo.u;
        }
    }
    __syncthreads();

    const int w = tid >> 6, lane = tid & 63;
    const int cl = lane & 15, quad = lane >> 4;

    // B column pointers (read direct from L2-resident Wsp)
    const f16* bptr[3];
    #pragma unroll
    for (int j = 0; j < 3; ++j) {
        int C = 48 * w + 16 * j + cl;
        bptr[j] = Wsp + (size_t)(mat0 + (C >> 6)) * 65536 + (size_t)(C & 63) * 1024;
    }

    f32x4 acc[3];
    #pragma unroll
    for (int j = 0; j < 3; ++j) acc[j] = 0.f;

    #pragma unroll
    for (int ks = 0; ks < 16; ++ks) {
        const int k0 = ks * 32 + quad * 8;
        half8 ah = *(const half8*)(As + cl * 1032 + k0);
        half8 al = *(const half8*)(As + cl * 1032 + 512 + k0);
        #pragma unroll
        for (int j = 0; j < 3; ++j) {
            half8 bh = *(const half8*)(bptr[j] + k0);
            half8 bl = *(const half8*)(bptr[j] + 512 + k0);
            acc[j] = __builtin_amdgcn_mfma_f32_16x16x32_f16(ah, bh, acc[j], 0, 0, 0);
            acc[j] = __builtin_amdgcn_mfma_f32_16x16x32_f16(ah, bl, acc[j], 0, 0, 0);
            acc[j] = __builtin_amdgcn_mfma_f32_16x16x32_f16(al, bh, acc[j], 0, 0, 0);
        }
    }

    const int bI = row0 / L_;
    const int rb = row0 - bI * L_;
    #pragma unroll
    for (int j = 0; j < 3; ++j) {
        const int cb   = 48 * w + 16 * j;
        const int mat  = cb >> 6;               // uniform per (w,j)
        const int mcol = (cb & 63) + cl;
        #pragma unroll
        for (int r = 0; r < 4; ++r) {
            int lrow = quad * 4 + r;
            float v  = acc[j][r];
            size_t grow = (size_t)(row0 + lrow);
            if (mat < 2) {
                f16* sp = (mat == 0) ? qsp : ksp;
                f16 hv = (f16)v;
                sp[grow * 128 + mcol]      = hv;
                sp[grow * 128 + 64 + mcol] = (f16)(v - (float)hv);
            } else {
                vhT[(size_t)(bI * 64 + mcol) * L_ + rb + lrow] = (f16)v;
            }
        }
    }
}

// ---------------------------------------------------------------------------
// k_dots: mid + edge dots via split-fp16 MFMA; 128x128 tiles; fp32 D/De.
// Q fragments direct from L2 (no Qs LDS). grid (72,18) x 256.
// ---------------------------------------------------------------------------
__global__ __launch_bounds__(256, 3) void k_dots(
    const f16* __restrict__ qsp, const f16* __restrict__ ksp,
    float* __restrict__ D32, float* __restrict__ G, float* __restrict__ De32)
{
    const int bx = blockIdx.x, by = blockIdx.y;
    const bool edge = (bx >= 64);
    int b, q0 = 0;
    size_t qrow0;
    if (!edge) {
        if (by >= 17) return;                 // NCOLS = 17 * 128
        b = bx >> 4;
        q0 = (bx * 128) & 2047;
        qrow0 = (size_t)b * L_ + S_ + q0;
    } else {
        int ex = bx - 64;
        b = ex >> 1;
        int half = ex & 1;
        if (half == 0 && by > 0) return;      // start rows see only cols <128
        qrow0 = (size_t)b * L_ + (half ? 2176 : 0);
    }
    const int col0 = by * 128;
    const size_t krow0 = (size_t)b * L_ + col0;

    __shared__ f16 Ks[128 * 136];
    const int tid = threadIdx.x;
    const int w = tid >> 6, lane = tid & 63;
    const int cl = lane & 15, quad = lane >> 4;

    // Q fragments direct from global (L2-resident qsp)
    half8 qh[2][2], qlo[2][2];
    #pragma unroll
    for (int rs = 0; rs < 2; ++rs)
        #pragma unroll
        for (int h = 0; h < 2; ++h) {
            const f16* qp = qsp + (qrow0 + 32 * w + 16 * rs + cl) * 128 + h * 32 + quad * 8;
            qh[rs][h]  = *(const half8*)qp;
            qlo[rs][h] = *(const half8*)(qp + 64);
        }

    #pragma unroll
    for (int i = 0; i < 8; ++i) {
        int g = tid + 256 * i;
        int r = g >> 4, c = g & 15;
        *(uint4*)(Ks + r * 136 + c * 8) = *(const uint4*)(ksp + (krow0 + r) * 128 + c * 8);
    }
    __syncthreads();

    f32x4 acc[2][8];
    #pragma unroll
    for (int i = 0; i < 2; ++i)
        #pragma unroll
        for (int j = 0; j < 8; ++j) acc[i][j] = 0.f;

    #pragma unroll
    for (int h = 0; h < 2; ++h) {
        #pragma unroll
        for (int cq = 0; cq < 2; ++cq) {
            half8 bh[4], bl[4];
            #pragma unroll
            for (int cc = 0; cc < 4; ++cc) {
                const f16* base = Ks + (16 * (cq * 4 + cc) + cl) * 136 + h * 32 + quad * 8;
                bh[cc] = *(const half8*)(base);
                bl[cc] = *(const half8*)(base + 64);
            }
            #pragma unroll
            for (int rs = 0; rs < 2; ++rs)
                #pragma unroll
                for (int cc = 0; cc < 4; ++cc) {
                    int c = cq * 4 + cc;
                    acc[rs][c] = __builtin_amdgcn_mfma_f32_16x16x32_f16(qh[rs][h], bh[cc], acc[rs][c], 0, 0, 0);
                    acc[rs][c] = __builtin_amdgcn_mfma_f32_16x16x32_f16(qh[rs][h], bl[cc], acc[rs][c], 0, 0, 0);
                    acc[rs][c] = __builtin_amdgcn_mfma_f32_16x16x32_f16(qlo[rs][h], bh[cc], acc[rs][c], 0, 0, 0);
                }
        }
    }

    if (!edge) {
        const int gr0 = bx * 128;
        const bool writeD = (by == 0) || ((by - 1) <= (q0 >> 7));
        if (writeD) {
            #pragma unroll
            for (int rs = 0; rs < 2; ++rs)
                #pragma unroll
                for (int c = 0; c < 8; ++c)
                    #pragma unroll
                    for (int r = 0; r < 4; ++r) {
                        int mrow = gr0 + 32 * w + 16 * rs + quad * 4 + r;
                        int n    = col0 + 16 * c + cl;
                        D32[(size_t)mrow * NCOLS + n] = acc[rs][c][r];
                    }
        }
        if (by >= 1) {
            const int chm = 2 * (by - 1);
            #pragma unroll
            for (int rs = 0; rs < 2; ++rs)
                #pragma unroll
                for (int r = 0; r < 4; ++r) {
                    float sA = 0.f, sB = 0.f;
                    #pragma unroll
                    for (int cc = 0; cc < 4; ++cc) {
                        sA += 1.f / (1.f + __expf(-acc[rs][cc][r]));
                        sB += 1.f / (1.f + __expf(-acc[rs][4 + cc][r]));
                    }
                    #pragma unroll
                    for (int off = 1; off < 16; off <<= 1) {
                        sA += __shfl_xor(sA, off);
                        sB += __shfl_xor(sB, off);
                    }
                    if (cl == 0) {
                        int row = gr0 + 32 * w + 16 * rs + quad * 4 + r;
                        G[(size_t)row * 32 + chm]     = sA;
                        G[(size_t)row * 32 + chm + 1] = sB;
                    }
                }
        }
    } else {
        const int er0 = (bx - 64) * 128;
        #pragma unroll
        for (int rs = 0; rs < 2; ++rs)
            #pragma unroll
            for (int c = 0; c < 8; ++c)
                #pragma unroll
                for (int r = 0; r < 4; ++r) {
                    int erow = er0 + 32 * w + 16 * rs + quad * 4 + r;
                    int n    = col0 + 16 * c + cl;
                    De32[(size_t)erow * LE + n] = acc[rs][c][r];
                }
    }
}

// ---------------------------------------------------------------------------
// k_scan: grid 9216 x 256. Reads exact fp32 dots; writes fp16 P.
// ---------------------------------------------------------------------------
__global__ __launch_bounds__(256) void k_scan(
    const f16* __restrict__ qsp, const float* __restrict__ cope,
    const float* __restrict__ G,
    const float* __restrict__ D32, f16* __restrict__ Dp,
    const float* __restrict__ De32, f16* __restrict__ Dep)
{
    __shared__ f16   qvh[128];
    __shared__ float li[128];
    __shared__ float Gs[32];
    __shared__ float Gsf[32];
    __shared__ float wmax[4], wsum[4];
    const int tid = threadIdx.x;
    const int gr  = blockIdx.x;
    const int lane = tid & 63, wid = tid >> 6;

    if (gr < NMID) {
        const int b = gr >> 11;
        const int q = gr & 2047;
        const size_t grow = (size_t)b * L_ + S_ + q;
        const int qlim = (q & ~63) + 64;

        if (tid < 16) ((uint4*)qvh)[tid] = ((const uint4*)(qsp + grow * 128))[tid];
        if (tid >= 16 && tid < 24)
            ((float4*)Gs)[tid - 16] = ((const float4*)G)[(size_t)gr * 8 + tid - 16];
        __syncthreads();
        if (tid < 128) {
            float a = 0.f;
            #pragma unroll
            for (int d = 0; d < DK; ++d)
                a += ((float)qvh[d] + (float)qvh[64 + d]) * cope[d * S_ + tid];
            li[tid] = a;
        }
        if (tid >= 128 && tid < 160) {
            int c = tid - 128;
            float s = 0.f;
            for (int cc = c + 1; cc < 32; ++cc) s += Gs[cc];
            Gsf[c] = s;
        }

        const float* Sr = D32 + (size_t)gr * NCOLS;
        f16* Dr = Dp + (size_t)gr * NCOLS;
        const int j0 = tid * 8;
        const int cg = tid >> 3, sl = tid & 7;
        float dot[8], gte[8];
        float csum = 0.f;
        if (j0 < qlim) {
            float4 t0 = *(const float4*)(Sr + 128 + j0);
            float4 t1 = *(const float4*)(Sr + 128 + j0 + 4);
            dot[0] = t0.x; dot[1] = t0.y; dot[2] = t0.z; dot[3] = t0.w;
            dot[4] = t1.x; dot[5] = t1.y; dot[6] = t1.z; dot[7] = t1.w;
            #pragma unroll
            for (int jj = 0; jj < 8; ++jj) {
                gte[jj] = 1.f / (1.f + __expf(-dot[jj]));
                csum += gte[jj];
            }
        } else {
            #pragma unroll
            for (int jj = 0; jj < 8; ++jj) { dot[jj] = 0.f; gte[jj] = 0.f; }
        }
        float sv = (tid < 128) ? Sr[tid] * SCALE : NEGINF;

        float inc = csum;
        #pragma unroll
        for (int off = 1; off < 8; off <<= 1) {
            float u = __shfl_down(inc, off, 8);
            if (sl + off < 8) inc += u;
        }
        __syncthreads();
        float run = (inc - csum) + Gsf[cg];

        float p8[8];
        #pragma unroll
        for (int jj = 7; jj >= 0; --jj) {
            run += gte[jj];
            float pos = fminf(run, (float)(S_ - 1));
            float pfl = floorf(pos);
            int ic  = (int)ceilf(pos);
            int ifl = (int)pfl;
            float w = pos - pfl;
            float bias = li[ic] * w + li[ifl] * (1.f - w);
            p8[jj] = (j0 + jj <= q) ? dot[jj] * SCALE + bias : NEGINF;
        }

        float mx = sv;
        #pragma unroll
        for (int jj = 0; jj < 8; ++jj) mx = fmaxf(mx, p8[jj]);
        #pragma unroll
        for (int off = 1; off < 64; off <<= 1) mx = fmaxf(mx, __shfl_xor(mx, off));
        if (lane == 0) wmax[wid] = mx;
        __syncthreads();
        mx = fmaxf(fmaxf(wmax[0], wmax[1]), fmaxf(wmax[2], wmax[3]));

        float lsum = 0.f;
        float e8[8];
        #pragma unroll
        for (int jj = 0; jj < 8; ++jj) {
            e8[jj] = __expf(p8[jj] - mx);
            lsum += e8[jj];
        }
        float es = 0.f;
        if (tid < 128) { es = __expf(sv - mx); lsum += es; }
        #pragma unroll
        for (int off = 1; off < 64; off <<= 1) lsum += __shfl_xor(lsum, off);
        if (lane == 0) wsum[wid] = lsum;
        __syncthreads();
        float inv = 1.f / (wsum[0] + wsum[1] + wsum[2] + wsum[3]);

        if (j0 < qlim) {
            U4 o;
            #pragma unroll
            for (int jj = 0; jj < 8; ++jj) o.h[jj] = (f16)(e8[jj] * inv);
            *(uint4*)(Dr + 128 + j0) = o.u;
        }
        if (tid < 128) Dr[tid] = (f16)(es * inv);
    } else {
        const int er = gr - NMID;
        const int r  = er & 255;
        const int Q  = (r < 128) ? r : (2048 + r);
        const float* Er32 = De32 + (size_t)er * LE;
        f16* Er = Dep + (size_t)er * LE;

        float v[9];
        #pragma unroll
        for (int i = 0; i < 9; ++i) {
            int j = tid + 256 * i;
            float d = Er32[j];
            v[i] = (j <= Q) ? d * SCALE : NEGINF;
        }
        float mx = v[0];
        #pragma unroll
        for (int i = 1; i < 9; ++i) mx = fmaxf(mx, v[i]);
        #pragma unroll
        for (int off = 1; off < 64; off <<= 1) mx = fmaxf(mx, __shfl_xor(mx, off));
        if (lane == 0) wmax[wid] = mx;
        __syncthreads();
        mx = fmaxf(fmaxf(wmax[0], wmax[1]), fmaxf(wmax[2], wmax[3]));

        float lsum = 0.f;
        #pragma unroll
        for (int i = 0; i < 9; ++i) {
            v[i] = __expf(v[i] - mx);
            lsum += v[i];
        }
        #pragma unroll
        for (int off = 1; off < 64; off <<= 1) lsum += __shfl_xor(lsum, off);
        if (lane == 0) wsum[wid] = lsum;
        __syncthreads();
        float inv = 1.f / (wsum[0] + wsum[1] + wsum[2] + wsum[3]);

        #pragma unroll
        for (int i = 0; i < 9; ++i)
            Er[tid + 256 * i] = (f16)(v[i] * inv);
    }
}

// ---------------------------------------------------------------------------
// k_pv: mid + edge PV, barrier-free main loop, in-block 4-way chunk split +
// merge; writes out directly. grid 288 x 512. P/V fragments direct from L2.
// ---------------------------------------------------------------------------
__global__ __launch_bounds__(512) void k_pv(
    const f16* __restrict__ Pmid, const f16* __restrict__ Pedge,
    const f16* __restrict__ vhT, float* __restrict__ out)
{
    __shared__ float mbuf[3][2][16 * 68];
    const int tid = threadIdx.x, bx = blockIdx.x;
    const int w = tid >> 6, lane = tid & 63;
    const int cl = lane & 15, quad = lane >> 4;
    const int g = w >> 2, ql = w & 3;
    const bool edge = (bx >= 256);

    const f16* Pb;
    size_t prow0, pitch;
    int b, cmax, cap, q0 = 0, r0 = 0;
    if (!edge) {
        int gr0 = bx * 32;
        b = gr0 >> 11; q0 = gr0 & 2047;
        Pb = Pmid; prow0 = gr0; pitch = NCOLS; cap = 34;
        cmax = (159 + q0) >> 6;
    } else {
        int er0 = (bx - 256) * 32;
        b = er0 >> 8; r0 = er0 & 255;
        Pb = Pedge; prow0 = er0; pitch = LE; cap = 36;
        int Qmax = (r0 < 128) ? (r0 + 31) : (2048 + r0 + 31);
        cmax = Qmax >> 6;
    }
    int c_end = cmax + 1;
    if (c_end > cap) c_end = cap;

    f32x4 acc[4];
    #pragma unroll
    for (int c = 0; c < 4; ++c) acc[c] = 0.f;

    for (int ch = ql; ch < c_end; ch += 4) {
        #pragma unroll
        for (int h = 0; h < 2; ++h) {
            half8 pa = *(const half8*)(Pb + (prow0 + 16 * g + cl) * pitch + ch * 64 + h * 32 + quad * 8);
            #pragma unroll
            for (int c2 = 0; c2 < 4; ++c2) {
                half8 bv = *(const half8*)(vhT + (size_t)(b * 64 + 16 * c2 + cl) * L_ + ch * 64 + h * 32 + quad * 8);
                acc[c2] = __builtin_amdgcn_mfma_f32_16x16x32_f16(pa, bv, acc[c2], 0, 0, 0);
            }
        }
    }

    if (ql != 0) {
        #pragma unroll
        for (int c2 = 0; c2 < 4; ++c2)
            #pragma unroll
            for (int r = 0; r < 4; ++r)
                mbuf[ql - 1][g][(quad * 4 + r) * 68 + 16 * c2 + cl] = acc[c2][r];
    }
    __syncthreads();
    if (ql == 0) {
        #pragma unroll
        for (int c2 = 0; c2 < 4; ++c2)
            #pragma unroll
            for (int r = 0; r < 4; ++r) {
                int idx = (quad * 4 + r) * 68 + 16 * c2 + cl;
                float v = acc[c2][r] + mbuf[0][g][idx] + mbuf[1][g][idx] + mbuf[2][g][idx];
                int lrow = 16 * g + quad * 4 + r;
                size_t grow;
                if (!edge) {
                    grow = (size_t)b * L_ + S_ + q0 + lrow;
                } else {
                    int rr = r0 + lrow;
                    int gQ = (rr < 128) ? rr : (2048 + rr);
                    grow = (size_t)b * L_ + gQ;
                }
                out[grow * DK + 16 * c2 + cl] = v;
            }
    }
}

// ---------------------------------------------------------------------------
extern "C" void kernel_launch(void* const* d_in, const int* in_sizes, int n_in,
                              void* d_out, int out_size, void* d_ws, size_t ws_size,
                              hipStream_t stream)
{
    const float* x    = (const float*)d_in[0];
    const float* Wq   = (const float*)d_in[1];
    const float* Wk   = (const float*)d_in[2];
    const float* Wv   = (const float*)d_in[3];
    const float* Wqs  = (const float*)d_in[4];
    const float* Wks  = (const float*)d_in[5];
    const float* Wvs  = (const float*)d_in[6];
    const float* Wqe  = (const float*)d_in[7];
    const float* Wke  = (const float*)d_in[8];
    const float* Wve  = (const float*)d_in[9];
    const float* g0   = (const float*)d_in[10];
    const float* b0   = (const float*)d_in[11];
    const float* gs   = (const float*)d_in[12];
    const float* bs   = (const float*)d_in[13];
    const float* ge   = (const float*)d_in[14];
    const float* be   = (const float*)d_in[15];
    const float* cope = (const float*)d_in[16];

    const size_t NR = (size_t)B_ * L_;               // 9216 rows
    f16*   qsp   = (f16*)d_ws;                       // NR*128 h (hi|lo)
    f16*   ksp   = qsp + NR * 128;                   // NR*128 h
    f16*   vhT   = ksp + NR * 128;                   // NR*64 h
    f16*   Wsp   = vhT + NR * 64;                    // 9*65536 h
    float* G     = (float*)(Wsp + (size_t)9 * 65536); // NMID*32 f32
    float* Dm32  = G + (size_t)NMID * 32;            // NMID*NCOLS f32 (raw dots)
    float* De32  = Dm32 + (size_t)NMID * NCOLS;      // NEDGE*LE f32 (raw dots)
    f16*   Dp    = (f16*)(De32 + (size_t)NEDGE * LE);// NMID*NCOLS h (P)
    f16*   Dep   = Dp + (size_t)NMID * NCOLS;        // NEDGE*LE h (P)
    float* out   = (float*)d_out;

    k_wsplit<<<dim3(8, 9), 256, 0, stream>>>(Wq, Wk, Wv, Wqs, Wks, Wvs,
                                             Wqe, Wke, Wve, Wsp);
    k_proj<<<576, 256, 0, stream>>>(x, Wsp, g0, b0, gs, bs, ge, be,
                                    qsp, ksp, vhT);
    k_dots<<<dim3(72, 18), 256, 0, stream>>>(qsp, ksp, Dm32, G, De32);
    k_scan<<<NMID + NEDGE, 256, 0, stream>>>(qsp, cope, G, Dm32, Dp, De32, Dep);
    k_pv<<<288, 512, 0, stream>>>(Dp, Dep, vhT, out);
}

// Round 7
// 205.604 us; speedup vs baseline: 1.2035x; 1.0946x over previous
//
#include <hip/hip_runtime.h>
#include <math.h>

#define B_    4
#define SEQ_  2048
#define S_    128
#define L_    2304          // SEQ + 2*S
#define DIN   512
#define DK    64
#define NEGINF (-1e30f)
#define SCALE 0.125f
#define NCOLS 2176          // start(128) + mid(2048) key columns in D
#define NMID  8192          // B_*SEQ_
#define NEDGE 1024          // B_*2*S_
#define LE    2304          // edge De row length

typedef _Float16 f16;
typedef __attribute__((ext_vector_type(8))) _Float16 half8;
typedef __attribute__((ext_vector_type(4))) float f32x4;

union U4 { uint4 u; f16 h[8]; half8 v; };

// ---------------------------------------------------------------------------
// k_wsplit: pre-split all 9 W matrices (512x64 f32) into fp16 hi/lo,
// transposed layout Wsp[mat][col][k: hi 0..511 | lo 512..1023].
// grid (8, 9) x 256.
// ---------------------------------------------------------------------------
__global__ __launch_bounds__(256) void k_wsplit(
    const float* __restrict__ Wq,  const float* __restrict__ Wk,  const float* __restrict__ Wv,
    const float* __restrict__ Wqs, const float* __restrict__ Wks, const float* __restrict__ Wvs,
    const float* __restrict__ Wqe, const float* __restrict__ Wke, const float* __restrict__ Wve,
    f16* __restrict__ Wsp)
{
    __shared__ float xs[64 * 68];
    const int kt  = blockIdx.x;
    const int mat = blockIdx.y;
    const float* W;
    switch (mat) {
        case 0: W = Wq;  break; case 1: W = Wk;  break; case 2: W = Wv;  break;
        case 3: W = Wqs; break; case 4: W = Wks; break; case 5: W = Wvs; break;
        case 6: W = Wqe; break; case 7: W = Wke; break; default: W = Wve; break;
    }
    const int tid = threadIdx.x;
    const int k0  = kt * 64;
    #pragma unroll
    for (int i = 0; i < 4; ++i) {
        int g = tid + 256 * i;
        int k = g >> 4, c4 = g & 15;
        *(float4*)(xs + k * 68 + c4 * 4) = ((const float4*)W)[(size_t)(k0 + k) * 16 + c4];
    }
    __syncthreads();
    const int col = tid & 63, hf = tid >> 6;
    const int kk0 = hf * 16;
    U4 hi0, hi1, lo0, lo1;
    #pragma unroll
    for (int j = 0; j < 8; ++j) {
        float v0 = xs[(kk0 + j) * 68 + col];
        float v1 = xs[(kk0 + 8 + j) * 68 + col];
        hi0.h[j] = (f16)v0; lo0.h[j] = (f16)(v0 - (float)hi0.h[j]);
        hi1.h[j] = (f16)v1; lo1.h[j] = (f16)(v1 - (float)hi1.h[j]);
    }
    f16* dst = Wsp + (size_t)mat * 65536 + (size_t)col * 1024 + k0 + kk0;
    *(uint4*)(dst)       = hi0.u;
    *(uint4*)(dst + 8)   = hi1.u;
    *(uint4*)(dst + 512) = lo0.u;
    *(uint4*)(dst + 520) = lo1.u;
}

// ---------------------------------------------------------------------------
// k_proj (round-2 verified version): fused LayerNorm + ALL THREE projections,
// cooperative LDS staging of A and B per k-step. grid 288 x 256.
// ---------------------------------------------------------------------------
__global__ __launch_bounds__(256) void k_proj(
    const float* __restrict__ x, const f16* __restrict__ Wsp,
    const float* __restrict__ g0, const float* __restrict__ b0,
    const float* __restrict__ gs, const float* __restrict__ bs,
    const float* __restrict__ ge, const float* __restrict__ be,
    f16* __restrict__ qsp, f16* __restrict__ ksp, f16* __restrict__ vhT)
{
    __shared__ f16 As[32 * 136];       // [row][hi 0..63 | lo 64..127 | pad]
    __shared__ f16 Bs[3 * 64 * 136];   // per-mat [col][hi|lo|pad]
    __shared__ float mean_s[32], rstd_s[32];
    const int tid  = threadIdx.x;
    const int row0 = blockIdx.x * 32;
    const int rseq = row0 % L_;
    const int seg  = (rseq < S_) ? 0 : (rseq >= L_ - S_) ? 2 : 1;
    const int mat0 = (seg == 0) ? 3 : (seg == 2) ? 6 : 0;
    const float* gg = (seg == 0) ? gs : (seg == 2) ? ge : g0;
    const float* bb = (seg == 0) ? bs : (seg == 2) ? be : b0;

    // row stats: 8 threads per row, 64 elems each
    {
        const int rr = tid >> 3, qq = tid & 7;
        const float4* xr = (const float4*)(x + (size_t)(row0 + rr) * DIN) + qq * 16;
        float s = 0.f, s2 = 0.f;
        #pragma unroll
        for (int i = 0; i < 16; ++i) {
            float4 v = xr[i];
            s  += v.x + v.y + v.z + v.w;
            s2 += v.x * v.x + v.y * v.y + v.z * v.z + v.w * v.w;
        }
        s  += __shfl_xor(s, 1);  s  += __shfl_xor(s, 2);  s  += __shfl_xor(s, 4);
        s2 += __shfl_xor(s2, 1); s2 += __shfl_xor(s2, 2); s2 += __shfl_xor(s2, 4);
        if (qq == 0) {
            float mean = s * (1.f / DIN);
            mean_s[rr] = mean;
            rstd_s[rr] = rsqrtf(s2 * (1.f / DIN) - mean * mean + 1e-5f);
        }
    }

    const int w = tid >> 6, lane = tid & 63;
    const int cl = lane & 15, quad = lane >> 4;
    const int r0 = 16 * (w >> 1), c0 = 32 * (w & 1);   // wave: 16 rows x 32 cols

    f32x4 acc[3][2];
    #pragma unroll
    for (int m = 0; m < 3; ++m)
        #pragma unroll
        for (int j = 0; j < 2; ++j) acc[m][j] = 0.f;

    for (int kc = 0; kc < DIN; kc += 64) {
        __syncthreads();
        // stage A (LN'd x, hi/lo split): 32 rows x 8 col-groups = 256 units
        {
            int r = tid >> 3, c8 = tid & 7;
            const float* xp = x + (size_t)(row0 + r) * DIN + kc + c8 * 8;
            float4 a0 = *(const float4*)xp;
            float4 a1 = *(const float4*)(xp + 4);
            float4 gA = *(const float4*)(gg + kc + c8 * 8);
            float4 gB = *(const float4*)(gg + kc + c8 * 8 + 4);
            float4 bA = *(const float4*)(bb + kc + c8 * 8);
            float4 bB = *(const float4*)(bb + kc + c8 * 8 + 4);
            float mean = mean_s[r], rstd = rstd_s[r];
            float n[8];
            n[0] = (a0.x - mean) * rstd * gA.x + bA.x;
            n[1] = (a0.y - mean) * rstd * gA.y + bA.y;
            n[2] = (a0.z - mean) * rstd * gA.z + bA.z;
            n[3] = (a0.w - mean) * rstd * gA.w + bA.w;
            n[4] = (a1.x - mean) * rstd * gB.x + bB.x;
            n[5] = (a1.y - mean) * rstd * gB.y + bB.y;
            n[6] = (a1.z - mean) * rstd * gB.z + bB.z;
            n[7] = (a1.w - mean) * rstd * gB.w + bB.w;
            U4 hi, lo;
            #pragma unroll
            for (int j = 0; j < 8; ++j) {
                hi.h[j] = (f16)n[j];
                lo.h[j] = (f16)(n[j] - (float)hi.h[j]);
            }
            *(uint4*)(As + r * 136 + c8 * 8)      = hi.u;
            *(uint4*)(As + r * 136 + 64 + c8 * 8) = lo.u;
        }
        // stage B for all 3 mats: 3 x 64 cols x 8 groups = 1536 units
        #pragma unroll
        for (int i = 0; i < 6; ++i) {
            int g = tid + 256 * i;
            int mm = g >> 9, rem = g & 511;
            int col = rem >> 3, c8 = rem & 7;
            const f16* src = Wsp + (size_t)(mat0 + mm) * 65536 + (size_t)col * 1024 + kc + c8 * 8;
            f16* dst = Bs + mm * 8704 + col * 136 + c8 * 8;
            *(uint4*)(dst)      = *(const uint4*)(src);
            *(uint4*)(dst + 64) = *(const uint4*)(src + 512);
        }
        __syncthreads();
        #pragma unroll
        for (int h = 0; h < 2; ++h) {
            half8 ah, al;
            {
                const f16* base = As + (r0 + cl) * 136 + h * 32 + quad * 8;
                ah = *(const half8*)(base);
                al = *(const half8*)(base + 64);
            }
            #pragma unroll
            for (int m = 0; m < 3; ++m)
                #pragma unroll
                for (int cs = 0; cs < 2; ++cs) {
                    const f16* base = Bs + m * 8704 + (c0 + 16 * cs + cl) * 136 + h * 32 + quad * 8;
                    half8 bh = *(const half8*)(base);
                    half8 bl = *(const half8*)(base + 64);
                    acc[m][cs] = __builtin_amdgcn_mfma_f32_16x16x32_f16(ah, bh, acc[m][cs], 0, 0, 0);
                    acc[m][cs] = __builtin_amdgcn_mfma_f32_16x16x32_f16(ah, bl, acc[m][cs], 0, 0, 0);
                    acc[m][cs] = __builtin_amdgcn_mfma_f32_16x16x32_f16(al, bh, acc[m][cs], 0, 0, 0);
                }
        }
    }

    const int bI = row0 / L_;
    const int rb = row0 - bI * L_;
    #pragma unroll
    for (int m = 0; m < 3; ++m) {
        f16* sp = (m == 0) ? qsp : ksp;
        #pragma unroll
        for (int cs = 0; cs < 2; ++cs)
            #pragma unroll
            for (int r = 0; r < 4; ++r) {
                int lrow = r0 + quad * 4 + r;
                int col  = c0 + 16 * cs + cl;
                float v  = acc[m][cs][r];
                size_t grow = (size_t)(row0 + lrow);
                if (m < 2) {
                    f16 hv = (f16)v;
                    sp[grow * 128 + col]      = hv;
                    sp[grow * 128 + 64 + col] = (f16)(v - (float)hv);
                } else {
                    vhT[(size_t)(bI * 64 + col) * L_ + rb + lrow] = (f16)v;
                }
            }
    }
}

// ---------------------------------------------------------------------------
// k_dots: mid + edge dots via split-fp16 MFMA; 128x128 tiles; fp32 D/De.
// Q fragments direct from L2 (no Qs LDS). grid (72,18) x 256.
// ---------------------------------------------------------------------------
__global__ __launch_bounds__(256, 3) void k_dots(
    const f16* __restrict__ qsp, const f16* __restrict__ ksp,
    float* __restrict__ D32, float* __restrict__ G, float* __restrict__ De32)
{
    const int bx = blockIdx.x, by = blockIdx.y;
    const bool edge = (bx >= 64);
    int b, q0 = 0;
    size_t qrow0;
    if (!edge) {
        if (by >= 17) return;                 // NCOLS = 17 * 128
        b = bx >> 4;
        q0 = (bx * 128) & 2047;
        qrow0 = (size_t)b * L_ + S_ + q0;
    } else {
        int ex = bx - 64;
        b = ex >> 1;
        int half = ex & 1;
        if (half == 0 && by > 0) return;      // start rows see only cols <128
        qrow0 = (size_t)b * L_ + (half ? 2176 : 0);
    }
    const int col0 = by * 128;
    const size_t krow0 = (size_t)b * L_ + col0;

    __shared__ f16 Ks[128 * 136];
    const int tid = threadIdx.x;
    const int w = tid >> 6, lane = tid & 63;
    const int cl = lane & 15, quad = lane >> 4;

    // Q fragments direct from global (L2-resident qsp)
    half8 qh[2][2], qlo[2][2];
    #pragma unroll
    for (int rs = 0; rs < 2; ++rs)
        #pragma unroll
        for (int h = 0; h < 2; ++h) {
            const f16* qp = qsp + (qrow0 + 32 * w + 16 * rs + cl) * 128 + h * 32 + quad * 8;
            qh[rs][h]  = *(const half8*)qp;
            qlo[rs][h] = *(const half8*)(qp + 64);
        }

    #pragma unroll
    for (int i = 0; i < 8; ++i) {
        int g = tid + 256 * i;
        int r = g >> 4, c = g & 15;
        *(uint4*)(Ks + r * 136 + c * 8) = *(const uint4*)(ksp + (krow0 + r) * 128 + c * 8);
    }
    __syncthreads();

    f32x4 acc[2][8];
    #pragma unroll
    for (int i = 0; i < 2; ++i)
        #pragma unroll
        for (int j = 0; j < 8; ++j) acc[i][j] = 0.f;

    #pragma unroll
    for (int h = 0; h < 2; ++h) {
        #pragma unroll
        for (int cq = 0; cq < 2; ++cq) {
            half8 bh[4], bl[4];
            #pragma unroll
            for (int cc = 0; cc < 4; ++cc) {
                const f16* base = Ks + (16 * (cq * 4 + cc) + cl) * 136 + h * 32 + quad * 8;
                bh[cc] = *(const half8*)(base);
                bl[cc] = *(const half8*)(base + 64);
            }
            #pragma unroll
            for (int rs = 0; rs < 2; ++rs)
                #pragma unroll
                for (int cc = 0; cc < 4; ++cc) {
                    int c = cq * 4 + cc;
                    acc[rs][c] = __builtin_amdgcn_mfma_f32_16x16x32_f16(qh[rs][h], bh[cc], acc[rs][c], 0, 0, 0);
                    acc[rs][c] = __builtin_amdgcn_mfma_f32_16x16x32_f16(qh[rs][h], bl[cc], acc[rs][c], 0, 0, 0);
                    acc[rs][c] = __builtin_amdgcn_mfma_f32_16x16x32_f16(qlo[rs][h], bh[cc], acc[rs][c], 0, 0, 0);
                }
        }
    }

    if (!edge) {
        const int gr0 = bx * 128;
        const bool writeD = (by == 0) || ((by - 1) <= (q0 >> 7));
        if (writeD) {
            #pragma unroll
            for (int rs = 0; rs < 2; ++rs)
                #pragma unroll
                for (int c = 0; c < 8; ++c)
                    #pragma unroll
                    for (int r = 0; r < 4; ++r) {
                        int mrow = gr0 + 32 * w + 16 * rs + quad * 4 + r;
                        int n    = col0 + 16 * c + cl;
                        D32[(size_t)mrow * NCOLS + n] = acc[rs][c][r];
                    }
        }
        if (by >= 1) {
            const int chm = 2 * (by - 1);
            #pragma unroll
            for (int rs = 0; rs < 2; ++rs)
                #pragma unroll
                for (int r = 0; r < 4; ++r) {
                    float sA = 0.f, sB = 0.f;
                    #pragma unroll
                    for (int cc = 0; cc < 4; ++cc) {
                        sA += 1.f / (1.f + __expf(-acc[rs][cc][r]));
                        sB += 1.f / (1.f + __expf(-acc[rs][4 + cc][r]));
                    }
                    #pragma unroll
                    for (int off = 1; off < 16; off <<= 1) {
                        sA += __shfl_xor(sA, off);
                        sB += __shfl_xor(sB, off);
                    }
                    if (cl == 0) {
                        int row = gr0 + 32 * w + 16 * rs + quad * 4 + r;
                        G[(size_t)row * 32 + chm]     = sA;
                        G[(size_t)row * 32 + chm + 1] = sB;
                    }
                }
        }
    } else {
        const int er0 = (bx - 64) * 128;
        #pragma unroll
        for (int rs = 0; rs < 2; ++rs)
            #pragma unroll
            for (int c = 0; c < 8; ++c)
                #pragma unroll
                for (int r = 0; r < 4; ++r) {
                    int erow = er0 + 32 * w + 16 * rs + quad * 4 + r;
                    int n    = col0 + 16 * c + cl;
                    De32[(size_t)erow * LE + n] = acc[rs][c][r];
                }
    }
}

// ---------------------------------------------------------------------------
// k_scan: grid 9216 x 256. Reads exact fp32 dots; writes fp16 P.
// ---------------------------------------------------------------------------
__global__ __launch_bounds__(256) void k_scan(
    const f16* __restrict__ qsp, const float* __restrict__ cope,
    const float* __restrict__ G,
    const float* __restrict__ D32, f16* __restrict__ Dp,
    const float* __restrict__ De32, f16* __restrict__ Dep)
{
    __shared__ f16   qvh[128];
    __shared__ float li[128];
    __shared__ float Gs[32];
    __shared__ float Gsf[32];
    __shared__ float wmax[4], wsum[4];
    const int tid = threadIdx.x;
    const int gr  = blockIdx.x;
    const int lane = tid & 63, wid = tid >> 6;

    if (gr < NMID) {
        const int b = gr >> 11;
        const int q = gr & 2047;
        const size_t grow = (size_t)b * L_ + S_ + q;
        const int qlim = (q & ~63) + 64;

        if (tid < 16) ((uint4*)qvh)[tid] = ((const uint4*)(qsp + grow * 128))[tid];
        if (tid >= 16 && tid < 24)
            ((float4*)Gs)[tid - 16] = ((const float4*)G)[(size_t)gr * 8 + tid - 16];
        __syncthreads();
        if (tid < 128) {
            float a = 0.f;
            #pragma unroll
            for (int d = 0; d < DK; ++d)
                a += ((float)qvh[d] + (float)qvh[64 + d]) * cope[d * S_ + tid];
            li[tid] = a;
        }
        if (tid >= 128 && tid < 160) {
            int c = tid - 128;
            float s = 0.f;
            for (int cc = c + 1; cc < 32; ++cc) s += Gs[cc];
            Gsf[c] = s;
        }

        const float* Sr = D32 + (size_t)gr * NCOLS;
        f16* Dr = Dp + (size_t)gr * NCOLS;
        const int j0 = tid * 8;
        const int cg = tid >> 3, sl = tid & 7;
        float dot[8], gte[8];
        float csum = 0.f;
        if (j0 < qlim) {
            float4 t0 = *(const float4*)(Sr + 128 + j0);
            float4 t1 = *(const float4*)(Sr + 128 + j0 + 4);
            dot[0] = t0.x; dot[1] = t0.y; dot[2] = t0.z; dot[3] = t0.w;
            dot[4] = t1.x; dot[5] = t1.y; dot[6] = t1.z; dot[7] = t1.w;
            #pragma unroll
            for (int jj = 0; jj < 8; ++jj) {
                gte[jj] = 1.f / (1.f + __expf(-dot[jj]));
                csum += gte[jj];
            }
        } else {
            #pragma unroll
            for (int jj = 0; jj < 8; ++jj) { dot[jj] = 0.f; gte[jj] = 0.f; }
        }
        float sv = (tid < 128) ? Sr[tid] * SCALE : NEGINF;

        float inc = csum;
        #pragma unroll
        for (int off = 1; off < 8; off <<= 1) {
            float u = __shfl_down(inc, off, 8);
            if (sl + off < 8) inc += u;
        }
        __syncthreads();
        float run = (inc - csum) + Gsf[cg];

        float p8[8];
        #pragma unroll
        for (int jj = 7; jj >= 0; --jj) {
            run += gte[jj];
            float pos = fminf(run, (float)(S_ - 1));
            float pfl = floorf(pos);
            int ic  = (int)ceilf(pos);
            int ifl = (int)pfl;
            float w = pos - pfl;
            float bias = li[ic] * w + li[ifl] * (1.f - w);
            p8[jj] = (j0 + jj <= q) ? dot[jj] * SCALE + bias : NEGINF;
        }

        float mx = sv;
        #pragma unroll
        for (int jj = 0; jj < 8; ++jj) mx = fmaxf(mx, p8[jj]);
        #pragma unroll
        for (int off = 1; off < 64; off <<= 1) mx = fmaxf(mx, __shfl_xor(mx, off));
        if (lane == 0) wmax[wid] = mx;
        __syncthreads();
        mx = fmaxf(fmaxf(wmax[0], wmax[1]), fmaxf(wmax[2], wmax[3]));

        float lsum = 0.f;
        float e8[8];
        #pragma unroll
        for (int jj = 0; jj < 8; ++jj) {
            e8[jj] = __expf(p8[jj] - mx);
            lsum += e8[jj];
        }
        float es = 0.f;
        if (tid < 128) { es = __expf(sv - mx); lsum += es; }
        #pragma unroll
        for (int off = 1; off < 64; off <<= 1) lsum += __shfl_xor(lsum, off);
        if (lane == 0) wsum[wid] = lsum;
        __syncthreads();
        float inv = 1.f / (wsum[0] + wsum[1] + wsum[2] + wsum[3]);

        if (j0 < qlim) {
            U4 o;
            #pragma unroll
            for (int jj = 0; jj < 8; ++jj) o.h[jj] = (f16)(e8[jj] * inv);
            *(uint4*)(Dr + 128 + j0) = o.u;
        }
        if (tid < 128) Dr[tid] = (f16)(es * inv);
    } else {
        const int er = gr - NMID;
        const int r  = er & 255;
        const int Q  = (r < 128) ? r : (2048 + r);
        const float* Er32 = De32 + (size_t)er * LE;
        f16* Er = Dep + (size_t)er * LE;

        float v[9];
        #pragma unroll
        for (int i = 0; i < 9; ++i) {
            int j = tid + 256 * i;
            float d = Er32[j];
            v[i] = (j <= Q) ? d * SCALE : NEGINF;
        }
        float mx = v[0];
        #pragma unroll
        for (int i = 1; i < 9; ++i) mx = fmaxf(mx, v[i]);
        #pragma unroll
        for (int off = 1; off < 64; off <<= 1) mx = fmaxf(mx, __shfl_xor(mx, off));
        if (lane == 0) wmax[wid] = mx;
        __syncthreads();
        mx = fmaxf(fmaxf(wmax[0], wmax[1]), fmaxf(wmax[2], wmax[3]));

        float lsum = 0.f;
        #pragma unroll
        for (int i = 0; i < 9; ++i) {
            v[i] = __expf(v[i] - mx);
            lsum += v[i];
        }
        #pragma unroll
        for (int off = 1; off < 64; off <<= 1) lsum += __shfl_xor(lsum, off);
        if (lane == 0) wsum[wid] = lsum;
        __syncthreads();
        float inv = 1.f / (wsum[0] + wsum[1] + wsum[2] + wsum[3]);

        #pragma unroll
        for (int i = 0; i < 9; ++i)
            Er[tid + 256 * i] = (f16)(v[i] * inv);
    }
}

// ---------------------------------------------------------------------------
// k_pv: mid + edge PV, barrier-free main loop, in-block 4-way chunk split +
// merge; writes out directly. grid 288 x 512. P/V fragments direct from L2.
// ---------------------------------------------------------------------------
__global__ __launch_bounds__(512) void k_pv(
    const f16* __restrict__ Pmid, const f16* __restrict__ Pedge,
    const f16* __restrict__ vhT, float* __restrict__ out)
{
    __shared__ float mbuf[3][2][16 * 68];
    const int tid = threadIdx.x, bx = blockIdx.x;
    const int w = tid >> 6, lane = tid & 63;
    const int cl = lane & 15, quad = lane >> 4;
    const int g = w >> 2, ql = w & 3;
    const bool edge = (bx >= 256);

    const f16* Pb;
    size_t prow0, pitch;
    int b, cmax, cap, q0 = 0, r0 = 0;
    if (!edge) {
        int gr0 = bx * 32;
        b = gr0 >> 11; q0 = gr0 & 2047;
        Pb = Pmid; prow0 = gr0; pitch = NCOLS; cap = 34;
        cmax = (159 + q0) >> 6;
    } else {
        int er0 = (bx - 256) * 32;
        b = er0 >> 8; r0 = er0 & 255;
        Pb = Pedge; prow0 = er0; pitch = LE; cap = 36;
        int Qmax = (r0 < 128) ? (r0 + 31) : (2048 + r0 + 31);
        cmax = Qmax >> 6;
    }
    int c_end = cmax + 1;
    if (c_end > cap) c_end = cap;

    f32x4 acc[4];
    #pragma unroll
    for (int c = 0; c < 4; ++c) acc[c] = 0.f;

    for (int ch = ql; ch < c_end; ch += 4) {
        #pragma unroll
        for (int h = 0; h < 2; ++h) {
            half8 pa = *(const half8*)(Pb + (prow0 + 16 * g + cl) * pitch + ch * 64 + h * 32 + quad * 8);
            #pragma unroll
            for (int c2 = 0; c2 < 4; ++c2) {
                half8 bv = *(const half8*)(vhT + (size_t)(b * 64 + 16 * c2 + cl) * L_ + ch * 64 + h * 32 + quad * 8);
                acc[c2] = __builtin_amdgcn_mfma_f32_16x16x32_f16(pa, bv, acc[c2], 0, 0, 0);
            }
        }
    }

    if (ql != 0) {
        #pragma unroll
        for (int c2 = 0; c2 < 4; ++c2)
            #pragma unroll
            for (int r = 0; r < 4; ++r)
                mbuf[ql - 1][g][(quad * 4 + r) * 68 + 16 * c2 + cl] = acc[c2][r];
    }
    __syncthreads();
    if (ql == 0) {
        #pragma unroll
        for (int c2 = 0; c2 < 4; ++c2)
            #pragma unroll
            for (int r = 0; r < 4; ++r) {
                int idx = (quad * 4 + r) * 68 + 16 * c2 + cl;
                float v = acc[c2][r] + mbuf[0][g][idx] + mbuf[1][g][idx] + mbuf[2][g][idx];
                int lrow = 16 * g + quad * 4 + r;
                size_t grow;
                if (!edge) {
                    grow = (size_t)b * L_ + S_ + q0 + lrow;
                } else {
                    int rr = r0 + lrow;
                    int gQ = (rr < 128) ? rr : (2048 + rr);
                    grow = (size_t)b * L_ + gQ;
                }
                out[grow * DK + 16 * c2 + cl] = v;
            }
    }
}

// ---------------------------------------------------------------------------
extern "C" void kernel_launch(void* const* d_in, const int* in_sizes, int n_in,
                              void* d_out, int out_size, void* d_ws, size_t ws_size,
                              hipStream_t stream)
{
    const float* x    = (const float*)d_in[0];
    const float* Wq   = (const float*)d_in[1];
    const float* Wk   = (const float*)d_in[2];
    const float* Wv   = (const float*)d_in[3];
    const float* Wqs  = (const float*)d_in[4];
    const float* Wks  = (const float*)d_in[5];
    const float* Wvs  = (const float*)d_in[6];
    const float* Wqe  = (const float*)d_in[7];
    const float* Wke  = (const float*)d_in[8];
    const float* Wve  = (const float*)d_in[9];
    const float* g0   = (const float*)d_in[10];
    const float* b0   = (const float*)d_in[11];
    const float* gs   = (const float*)d_in[12];
    const float* bs   = (const float*)d_in[13];
    const float* ge   = (const float*)d_in[14];
    const float* be   = (const float*)d_in[15];
    const float* cope = (const float*)d_in[16];

    const size_t NR = (size_t)B_ * L_;               // 9216 rows
    f16*   qsp   = (f16*)d_ws;                       // NR*128 h (hi|lo)
    f16*   ksp   = qsp + NR * 128;                   // NR*128 h
    f16*   vhT   = ksp + NR * 128;                   // NR*64 h
    f16*   Wsp   = vhT + NR * 64;                    // 9*65536 h
    float* G     = (float*)(Wsp + (size_t)9 * 65536); // NMID*32 f32
    float* Dm32  = G + (size_t)NMID * 32;            // NMID*NCOLS f32 (raw dots)
    float* De32  = Dm32 + (size_t)NMID * NCOLS;      // NEDGE*LE f32 (raw dots)
    f16*   Dp    = (f16*)(De32 + (size_t)NEDGE * LE);// NMID*NCOLS h (P)
    f16*   Dep   = Dp + (size_t)NMID * NCOLS;        // NEDGE*LE h (P)
    float* out   = (float*)d_out;

    k_wsplit<<<dim3(8, 9), 256, 0, stream>>>(Wq, Wk, Wv, Wqs, Wks, Wvs,
                                             Wqe, Wke, Wve, Wsp);
    k_proj<<<288, 256, 0, stream>>>(x, Wsp, g0, b0, gs, bs, ge, be,
                                    qsp, ksp, vhT);
    k_dots<<<dim3(72, 18), 256, 0, stream>>>(qsp, ksp, Dm32, G, De32);
    k_scan<<<NMID + NEDGE, 256, 0, stream>>>(qsp, cope, G, Dm32, Dp, De32, Dep);
    k_pv<<<288, 512, 0, stream>>>(Dp, Dep, vhT, out);
}

// Round 8
// 192.069 us; speedup vs baseline: 1.2883x; 1.0705x over previous
//
#include <hip/hip_runtime.h>
#include <math.h>

#define B_    4
#define SEQ_  2048
#define S_    128
#define L_    2304          // SEQ + 2*S
#define DIN   512
#define DK    64
#define NEGINF (-1e30f)
#define SCALE 0.125f
#define NCOLS 2176          // start(128) + mid(2048) key columns in D
#define NMID  8192          // B_*SEQ_
#define NEDGE 1024          // B_*2*S_
#define LE    2304          // edge De row length

typedef _Float16 f16;
typedef __attribute__((ext_vector_type(8))) _Float16 half8;
typedef __attribute__((ext_vector_type(4))) float f32x4;

union U4 { uint4 u; f16 h[8]; half8 v; };

// ---------------------------------------------------------------------------
// k_wsplit: pre-split 9 W matrices into fp16 hi/lo (transposed) + cope split.
// grid (8, 10) x 256. mat==9: cope (64x128) -> copesp[p][hi d | lo d].
// ---------------------------------------------------------------------------
__global__ __launch_bounds__(256) void k_wsplit(
    const float* __restrict__ Wq,  const float* __restrict__ Wk,  const float* __restrict__ Wv,
    const float* __restrict__ Wqs, const float* __restrict__ Wks, const float* __restrict__ Wvs,
    const float* __restrict__ Wqe, const float* __restrict__ Wke, const float* __restrict__ Wve,
    const float* __restrict__ cope,
    f16* __restrict__ Wsp, f16* __restrict__ copesp)
{
    __shared__ float xs[64 * 68];
    const int kt  = blockIdx.x;
    const int mat = blockIdx.y;
    const int tid = threadIdx.x;

    if (mat == 9) {
        if (kt != 0) return;
        for (int half = 0; half < 2; ++half) {
            #pragma unroll
            for (int i = 0; i < 4; ++i) {
                int g = tid + 256 * i;          // 64 d x 16 float4
                int d = g >> 4, p4 = g & 15;
                *(float4*)(xs + d * 68 + p4 * 4) =
                    *(const float4*)(cope + (size_t)d * 128 + half * 64 + p4 * 4);
            }
            __syncthreads();
            if (tid < 128) {
                int pp = tid & 63, hf = tid >> 6;   // 2 halves of d
                int d0 = hf * 32;
                for (int j = 0; j < 32; ++j) {
                    float v = xs[(d0 + j) * 68 + pp];
                    f16 hi = (f16)v;
                    copesp[(size_t)(half * 64 + pp) * 128 + d0 + j]      = hi;
                    copesp[(size_t)(half * 64 + pp) * 128 + 64 + d0 + j] = (f16)(v - (float)hi);
                }
            }
            __syncthreads();
        }
        return;
    }

    const float* W;
    switch (mat) {
        case 0: W = Wq;  break; case 1: W = Wk;  break; case 2: W = Wv;  break;
        case 3: W = Wqs; break; case 4: W = Wks; break; case 5: W = Wvs; break;
        case 6: W = Wqe; break; case 7: W = Wke; break; default: W = Wve; break;
    }
    const int k0  = kt * 64;
    #pragma unroll
    for (int i = 0; i < 4; ++i) {
        int g = tid + 256 * i;
        int k = g >> 4, c4 = g & 15;
        *(float4*)(xs + k * 68 + c4 * 4) = ((const float4*)W)[(size_t)(k0 + k) * 16 + c4];
    }
    __syncthreads();
    const int col = tid & 63, hf = tid >> 6;
    const int kk0 = hf * 16;
    U4 hi0, hi1, lo0, lo1;
    #pragma unroll
    for (int j = 0; j < 8; ++j) {
        float v0 = xs[(kk0 + j) * 68 + col];
        float v1 = xs[(kk0 + 8 + j) * 68 + col];
        hi0.h[j] = (f16)v0; lo0.h[j] = (f16)(v0 - (float)hi0.h[j]);
        hi1.h[j] = (f16)v1; lo1.h[j] = (f16)(v1 - (float)hi1.h[j]);
    }
    f16* dst = Wsp + (size_t)mat * 65536 + (size_t)col * 1024 + k0 + kk0;
    *(uint4*)(dst)       = hi0.u;
    *(uint4*)(dst + 8)   = hi1.u;
    *(uint4*)(dst + 512) = lo0.u;
    *(uint4*)(dst + 520) = lo1.u;
}

// ---------------------------------------------------------------------------
// k_proj (round-2 verified): fused LayerNorm + all three projections,
// cooperative LDS staging of A and B per k-step. grid 288 x 256.
// ---------------------------------------------------------------------------
__global__ __launch_bounds__(256) void k_proj(
    const float* __restrict__ x, const f16* __restrict__ Wsp,
    const float* __restrict__ g0, const float* __restrict__ b0,
    const float* __restrict__ gs, const float* __restrict__ bs,
    const float* __restrict__ ge, const float* __restrict__ be,
    f16* __restrict__ qsp, f16* __restrict__ ksp, f16* __restrict__ vhT)
{
    __shared__ f16 As[32 * 136];       // [row][hi 0..63 | lo 64..127 | pad]
    __shared__ f16 Bs[3 * 64 * 136];   // per-mat [col][hi|lo|pad]
    __shared__ float mean_s[32], rstd_s[32];
    const int tid  = threadIdx.x;
    const int row0 = blockIdx.x * 32;
    const int rseq = row0 % L_;
    const int seg  = (rseq < S_) ? 0 : (rseq >= L_ - S_) ? 2 : 1;
    const int mat0 = (seg == 0) ? 3 : (seg == 2) ? 6 : 0;
    const float* gg = (seg == 0) ? gs : (seg == 2) ? ge : g0;
    const float* bb = (seg == 0) ? bs : (seg == 2) ? be : b0;

    // row stats: 8 threads per row, 64 elems each
    {
        const int rr = tid >> 3, qq = tid & 7;
        const float4* xr = (const float4*)(x + (size_t)(row0 + rr) * DIN) + qq * 16;
        float s = 0.f, s2 = 0.f;
        #pragma unroll
        for (int i = 0; i < 16; ++i) {
            float4 v = xr[i];
            s  += v.x + v.y + v.z + v.w;
            s2 += v.x * v.x + v.y * v.y + v.z * v.z + v.w * v.w;
        }
        s  += __shfl_xor(s, 1);  s  += __shfl_xor(s, 2);  s  += __shfl_xor(s, 4);
        s2 += __shfl_xor(s2, 1); s2 += __shfl_xor(s2, 2); s2 += __shfl_xor(s2, 4);
        if (qq == 0) {
            float mean = s * (1.f / DIN);
            mean_s[rr] = mean;
            rstd_s[rr] = rsqrtf(s2 * (1.f / DIN) - mean * mean + 1e-5f);
        }
    }

    const int w = tid >> 6, lane = tid & 63;
    const int cl = lane & 15, quad = lane >> 4;
    const int r0 = 16 * (w >> 1), c0 = 32 * (w & 1);   // wave: 16 rows x 32 cols

    f32x4 acc[3][2];
    #pragma unroll
    for (int m = 0; m < 3; ++m)
        #pragma unroll
        for (int j = 0; j < 2; ++j) acc[m][j] = 0.f;

    for (int kc = 0; kc < DIN; kc += 64) {
        __syncthreads();
        // stage A (LN'd x, hi/lo split): 32 rows x 8 col-groups = 256 units
        {
            int r = tid >> 3, c8 = tid & 7;
            const float* xp = x + (size_t)(row0 + r) * DIN + kc + c8 * 8;
            float4 a0 = *(const float4*)xp;
            float4 a1 = *(const float4*)(xp + 4);
            float4 gA = *(const float4*)(gg + kc + c8 * 8);
            float4 gB = *(const float4*)(gg + kc + c8 * 8 + 4);
            float4 bA = *(const float4*)(bb + kc + c8 * 8);
            float4 bB = *(const float4*)(bb + kc + c8 * 8 + 4);
            float mean = mean_s[r], rstd = rstd_s[r];
            float n[8];
            n[0] = (a0.x - mean) * rstd * gA.x + bA.x;
            n[1] = (a0.y - mean) * rstd * gA.y + bA.y;
            n[2] = (a0.z - mean) * rstd * gA.z + bA.z;
            n[3] = (a0.w - mean) * rstd * gA.w + bA.w;
            n[4] = (a1.x - mean) * rstd * gB.x + bB.x;
            n[5] = (a1.y - mean) * rstd * gB.y + bB.y;
            n[6] = (a1.z - mean) * rstd * gB.z + bB.z;
            n[7] = (a1.w - mean) * rstd * gB.w + bB.w;
            U4 hi, lo;
            #pragma unroll
            for (int j = 0; j < 8; ++j) {
                hi.h[j] = (f16)n[j];
                lo.h[j] = (f16)(n[j] - (float)hi.h[j]);
            }
            *(uint4*)(As + r * 136 + c8 * 8)      = hi.u;
            *(uint4*)(As + r * 136 + 64 + c8 * 8) = lo.u;
        }
        // stage B for all 3 mats: 3 x 64 cols x 8 groups = 1536 units
        #pragma unroll
        for (int i = 0; i < 6; ++i) {
            int g = tid + 256 * i;
            int mm = g >> 9, rem = g & 511;
            int col = rem >> 3, c8 = rem & 7;
            const f16* src = Wsp + (size_t)(mat0 + mm) * 65536 + (size_t)col * 1024 + kc + c8 * 8;
            f16* dst = Bs + mm * 8704 + col * 136 + c8 * 8;
            *(uint4*)(dst)      = *(const uint4*)(src);
            *(uint4*)(dst + 64) = *(const uint4*)(src + 512);
        }
        __syncthreads();
        #pragma unroll
        for (int h = 0; h < 2; ++h) {
            half8 ah, al;
            {
                const f16* base = As + (r0 + cl) * 136 + h * 32 + quad * 8;
                ah = *(const half8*)(base);
                al = *(const half8*)(base + 64);
            }
            #pragma unroll
            for (int m = 0; m < 3; ++m)
                #pragma unroll
                for (int cs = 0; cs < 2; ++cs) {
                    const f16* base = Bs + m * 8704 + (c0 + 16 * cs + cl) * 136 + h * 32 + quad * 8;
                    half8 bh = *(const half8*)(base);
                    half8 bl = *(const half8*)(base + 64);
                    acc[m][cs] = __builtin_amdgcn_mfma_f32_16x16x32_f16(ah, bh, acc[m][cs], 0, 0, 0);
                    acc[m][cs] = __builtin_amdgcn_mfma_f32_16x16x32_f16(ah, bl, acc[m][cs], 0, 0, 0);
                    acc[m][cs] = __builtin_amdgcn_mfma_f32_16x16x32_f16(al, bh, acc[m][cs], 0, 0, 0);
                }
        }
    }

    const int bI = row0 / L_;
    const int rb = row0 - bI * L_;
    #pragma unroll
    for (int m = 0; m < 3; ++m) {
        f16* sp = (m == 0) ? qsp : ksp;
        #pragma unroll
        for (int cs = 0; cs < 2; ++cs)
            #pragma unroll
            for (int r = 0; r < 4; ++r) {
                int lrow = r0 + quad * 4 + r;
                int col  = c0 + 16 * cs + cl;
                float v  = acc[m][cs][r];
                size_t grow = (size_t)(row0 + lrow);
                if (m < 2) {
                    f16 hv = (f16)v;
                    sp[grow * 128 + col]      = hv;
                    sp[grow * 128 + 64 + col] = (f16)(v - (float)hv);
                } else {
                    vhT[(size_t)(bI * 64 + col) * L_ + rb + lrow] = (f16)v;
                }
            }
    }
}

// ---------------------------------------------------------------------------
// k_li: li32[gr][p] = q[gr] . cope[:,p] for all mid rows, via split-fp16
// MFMA (3 terms). grid 256 x 256: 32 mid rows per block, 4 waves
// (wave: 16 rows x 64 pos).
// ---------------------------------------------------------------------------
__global__ __launch_bounds__(256) void k_li(
    const f16* __restrict__ qsp, const f16* __restrict__ copesp,
    float* __restrict__ li32)
{
    const int tid = threadIdx.x;
    const int w = tid >> 6, lane = tid & 63;
    const int cl = lane & 15, quad = lane >> 4;
    const int gr0 = blockIdx.x * 32;
    const int b = gr0 >> 11, q0 = gr0 & 2047;
    const size_t rowbase = (size_t)b * L_ + S_ + q0;
    const int rs = w >> 1;             // 16-row sub-tile
    const int p0 = 64 * (w & 1);       // pos base

    half8 ah[2], al[2];
    #pragma unroll
    for (int h = 0; h < 2; ++h) {
        const f16* qp = qsp + (rowbase + 16 * rs + cl) * 128 + h * 32 + quad * 8;
        ah[h] = *(const half8*)qp;
        al[h] = *(const half8*)(qp + 64);
    }

    f32x4 acc[4];
    #pragma unroll
    for (int cf = 0; cf < 4; ++cf) acc[cf] = 0.f;
    #pragma unroll
    for (int h = 0; h < 2; ++h)
        #pragma unroll
        for (int cf = 0; cf < 4; ++cf) {
            const f16* bbase = copesp + (size_t)(p0 + 16 * cf + cl) * 128 + h * 32 + quad * 8;
            half8 bh = *(const half8*)bbase;
            half8 bl = *(const half8*)(bbase + 64);
            acc[cf] = __builtin_amdgcn_mfma_f32_16x16x32_f16(ah[h], bh, acc[cf], 0, 0, 0);
            acc[cf] = __builtin_amdgcn_mfma_f32_16x16x32_f16(ah[h], bl, acc[cf], 0, 0, 0);
            acc[cf] = __builtin_amdgcn_mfma_f32_16x16x32_f16(al[h], bh, acc[cf], 0, 0, 0);
        }

    #pragma unroll
    for (int cf = 0; cf < 4; ++cf)
        #pragma unroll
        for (int r = 0; r < 4; ++r) {
            int row = 16 * rs + quad * 4 + r;
            int col = p0 + 16 * cf + cl;
            li32[(size_t)(gr0 + row) * 128 + col] = acc[cf][r];
        }
}

// ---------------------------------------------------------------------------
// k_dots (round-2 verified): mid + edge dots via split-fp16 MFMA; 128x128
// tiles; fp32 D/De; exact fp32 G sums. grid (72,18) x 256.
// ---------------------------------------------------------------------------
__global__ __launch_bounds__(256) void k_dots(
    const f16* __restrict__ qsp, const f16* __restrict__ ksp,
    float* __restrict__ D32, float* __restrict__ G, float* __restrict__ De32)
{
    const int bx = blockIdx.x, by = blockIdx.y;
    const bool edge = (bx >= 64);
    int b, q0 = 0;
    size_t qrow0;
    if (!edge) {
        if (by >= 17) return;                 // NCOLS = 17 * 128
        b = bx >> 4;
        q0 = (bx * 128) & 2047;
        qrow0 = (size_t)b * L_ + S_ + q0;
    } else {
        int ex = bx - 64;
        b = ex >> 1;
        int half = ex & 1;
        if (half == 0 && by > 0) return;      // start rows see only cols <128
        qrow0 = (size_t)b * L_ + (half ? 2176 : 0);
    }
    const int col0 = by * 128;
    const size_t krow0 = (size_t)b * L_ + col0;

    __shared__ f16 Qs[128 * 136];
    __shared__ f16 Ks[128 * 136];
    const int tid = threadIdx.x;

    #pragma unroll
    for (int i = 0; i < 8; ++i) {
        int g = tid + 256 * i;
        int r = g >> 4, c = g & 15;
        *(uint4*)(Qs + r * 136 + c * 8) = *(const uint4*)(qsp + (qrow0 + r) * 128 + c * 8);
        *(uint4*)(Ks + r * 136 + c * 8) = *(const uint4*)(ksp + (krow0 + r) * 128 + c * 8);
    }
    __syncthreads();

    const int w = tid >> 6, lane = tid & 63;
    const int cl = lane & 15, quad = lane >> 4;

    f32x4 acc[2][8];
    #pragma unroll
    for (int i = 0; i < 2; ++i)
        #pragma unroll
        for (int j = 0; j < 8; ++j) acc[i][j] = 0.f;

    #pragma unroll
    for (int h = 0; h < 2; ++h) {
        half8 ah[2], al[2];
        #pragma unroll
        for (int rs = 0; rs < 2; ++rs) {
            const f16* base = Qs + (32 * w + 16 * rs + cl) * 136 + h * 32 + quad * 8;
            ah[rs] = *(const half8*)(base);
            al[rs] = *(const half8*)(base + 64);
        }
        #pragma unroll
        for (int cq = 0; cq < 2; ++cq) {
            half8 bh[4], bl[4];
            #pragma unroll
            for (int cc = 0; cc < 4; ++cc) {
                const f16* base = Ks + (16 * (cq * 4 + cc) + cl) * 136 + h * 32 + quad * 8;
                bh[cc] = *(const half8*)(base);
                bl[cc] = *(const half8*)(base + 64);
            }
            #pragma unroll
            for (int rs = 0; rs < 2; ++rs)
                #pragma unroll
                for (int cc = 0; cc < 4; ++cc) {
                    int c = cq * 4 + cc;
                    acc[rs][c] = __builtin_amdgcn_mfma_f32_16x16x32_f16(ah[rs], bh[cc], acc[rs][c], 0, 0, 0);
                    acc[rs][c] = __builtin_amdgcn_mfma_f32_16x16x32_f16(ah[rs], bl[cc], acc[rs][c], 0, 0, 0);
                    acc[rs][c] = __builtin_amdgcn_mfma_f32_16x16x32_f16(al[rs], bh[cc], acc[rs][c], 0, 0, 0);
                }
        }
    }

    if (!edge) {
        const int gr0 = bx * 128;
        const bool writeD = (by == 0) || ((by - 1) <= (q0 >> 7));
        if (writeD) {
            #pragma unroll
            for (int rs = 0; rs < 2; ++rs)
                #pragma unroll
                for (int c = 0; c < 8; ++c)
                    #pragma unroll
                    for (int r = 0; r < 4; ++r) {
                        int mrow = gr0 + 32 * w + 16 * rs + quad * 4 + r;
                        int n    = col0 + 16 * c + cl;
                        D32[(size_t)mrow * NCOLS + n] = acc[rs][c][r];
                    }
        }
        if (by >= 1) {
            const int chm = 2 * (by - 1);
            #pragma unroll
            for (int rs = 0; rs < 2; ++rs)
                #pragma unroll
                for (int r = 0; r < 4; ++r) {
                    float sA = 0.f, sB = 0.f;
                    #pragma unroll
                    for (int cc = 0; cc < 4; ++cc) {
                        sA += 1.f / (1.f + __expf(-acc[rs][cc][r]));
                        sB += 1.f / (1.f + __expf(-acc[rs][4 + cc][r]));
                    }
                    #pragma unroll
                    for (int off = 1; off < 16; off <<= 1) {
                        sA += __shfl_xor(sA, off);
                        sB += __shfl_xor(sB, off);
                    }
                    if (cl == 0) {
                        int row = gr0 + 32 * w + 16 * rs + quad * 4 + r;
                        G[(size_t)row * 32 + chm]     = sA;
                        G[(size_t)row * 32 + chm + 1] = sB;
                    }
                }
        }
    } else {
        const int er0 = (bx - 64) * 128;
        #pragma unroll
        for (int rs = 0; rs < 2; ++rs)
            #pragma unroll
            for (int c = 0; c < 8; ++c)
                #pragma unroll
                for (int r = 0; r < 4; ++r) {
                    int erow = er0 + 32 * w + 16 * rs + quad * 4 + r;
                    int n    = col0 + 16 * c + cl;
                    De32[(size_t)erow * LE + n] = acc[rs][c][r];
                }
    }
}

// ---------------------------------------------------------------------------
// k_scan: grid 9216 x 256. Reads exact fp32 dots + precomputed li; fp16 P.
// ---------------------------------------------------------------------------
__global__ __launch_bounds__(256) void k_scan(
    const float* __restrict__ li32, const float* __restrict__ G,
    const float* __restrict__ D32, f16* __restrict__ Dp,
    const float* __restrict__ De32, f16* __restrict__ Dep)
{
    __shared__ float li[128];
    __shared__ float Gs[32];
    __shared__ float Gsf[32];
    __shared__ float wmax[4], wsum[4];
    const int tid = threadIdx.x;
    const int gr  = blockIdx.x;
    const int lane = tid & 63, wid = tid >> 6;

    if (gr < NMID) {
        const int b = gr >> 11;
        const int q = gr & 2047;
        const int qlim = (q & ~63) + 64;

        if (tid < 128) li[tid] = li32[(size_t)gr * 128 + tid];
        if (tid >= 128 && tid < 136)
            ((float4*)Gs)[tid - 128] = ((const float4*)G)[(size_t)gr * 8 + tid - 128];
        __syncthreads();
        if (tid >= 128 && tid < 160) {
            int c = tid - 128;
            float s = 0.f;
            for (int cc = c + 1; cc < 32; ++cc) s += Gs[cc];
            Gsf[c] = s;
        }

        const float* Sr = D32 + (size_t)gr * NCOLS;
        f16* Dr = Dp + (size_t)gr * NCOLS;
        const int j0 = tid * 8;
        const int cg = tid >> 3, sl = tid & 7;
        float dot[8], gte[8];
        float csum = 0.f;
        if (j0 < qlim) {
            float4 t0 = *(const float4*)(Sr + 128 + j0);
            float4 t1 = *(const float4*)(Sr + 128 + j0 + 4);
            dot[0] = t0.x; dot[1] = t0.y; dot[2] = t0.z; dot[3] = t0.w;
            dot[4] = t1.x; dot[5] = t1.y; dot[6] = t1.z; dot[7] = t1.w;
            #pragma unroll
            for (int jj = 0; jj < 8; ++jj) {
                gte[jj] = 1.f / (1.f + __expf(-dot[jj]));
                csum += gte[jj];
            }
        } else {
            #pragma unroll
            for (int jj = 0; jj < 8; ++jj) { dot[jj] = 0.f; gte[jj] = 0.f; }
        }
        float sv = (tid < 128) ? Sr[tid] * SCALE : NEGINF;

        float inc = csum;
        #pragma unroll
        for (int off = 1; off < 8; off <<= 1) {
            float u = __shfl_down(inc, off, 8);
            if (sl + off < 8) inc += u;
        }
        __syncthreads();
        float run = (inc - csum) + Gsf[cg];

        float p8[8];
        #pragma unroll
        for (int jj = 7; jj >= 0; --jj) {
            run += gte[jj];
            float pos = fminf(run, (float)(S_ - 1));
            float pfl = floorf(pos);
            int ic  = (int)ceilf(pos);
            int ifl = (int)pfl;
            float w = pos - pfl;
            float bias = li[ic] * w + li[ifl] * (1.f - w);
            p8[jj] = (j0 + jj <= q) ? dot[jj] * SCALE + bias : NEGINF;
        }

        float mx = sv;
        #pragma unroll
        for (int jj = 0; jj < 8; ++jj) mx = fmaxf(mx, p8[jj]);
        #pragma unroll
        for (int off = 1; off < 64; off <<= 1) mx = fmaxf(mx, __shfl_xor(mx, off));
        if (lane == 0) wmax[wid] = mx;
        __syncthreads();
        mx = fmaxf(fmaxf(wmax[0], wmax[1]), fmaxf(wmax[2], wmax[3]));

        float lsum = 0.f;
        float e8[8];
        #pragma unroll
        for (int jj = 0; jj < 8; ++jj) {
            e8[jj] = __expf(p8[jj] - mx);
            lsum += e8[jj];
        }
        float es = 0.f;
        if (tid < 128) { es = __expf(sv - mx); lsum += es; }
        #pragma unroll
        for (int off = 1; off < 64; off <<= 1) lsum += __shfl_xor(lsum, off);
        if (lane == 0) wsum[wid] = lsum;
        __syncthreads();
        float inv = 1.f / (wsum[0] + wsum[1] + wsum[2] + wsum[3]);

        if (j0 < qlim) {
            U4 o;
            #pragma unroll
            for (int jj = 0; jj < 8; ++jj) o.h[jj] = (f16)(e8[jj] * inv);
            *(uint4*)(Dr + 128 + j0) = o.u;
        }
        if (tid < 128) Dr[tid] = (f16)(es * inv);
    } else {
        const int er = gr - NMID;
        const int r  = er & 255;
        const int Q  = (r < 128) ? r : (2048 + r);
        const float* Er32 = De32 + (size_t)er * LE;
        f16* Er = Dep + (size_t)er * LE;

        float v[9];
        #pragma unroll
        for (int i = 0; i < 9; ++i) {
            int j = tid + 256 * i;
            float d = Er32[j];
            v[i] = (j <= Q) ? d * SCALE : NEGINF;
        }
        float mx = v[0];
        #pragma unroll
        for (int i = 1; i < 9; ++i) mx = fmaxf(mx, v[i]);
        #pragma unroll
        for (int off = 1; off < 64; off <<= 1) mx = fmaxf(mx, __shfl_xor(mx, off));
        if (lane == 0) wmax[wid] = mx;
        __syncthreads();
        mx = fmaxf(fmaxf(wmax[0], wmax[1]), fmaxf(wmax[2], wmax[3]));

        float lsum = 0.f;
        #pragma unroll
        for (int i = 0; i < 9; ++i) {
            v[i] = __expf(v[i] - mx);
            lsum += v[i];
        }
        #pragma unroll
        for (int off = 1; off < 64; off <<= 1) lsum += __shfl_xor(lsum, off);
        if (lane == 0) wsum[wid] = lsum;
        __syncthreads();
        float inv = 1.f / (wsum[0] + wsum[1] + wsum[2] + wsum[3]);

        #pragma unroll
        for (int i = 0; i < 9; ++i)
            Er[tid + 256 * i] = (f16)(v[i] * inv);
    }
}

// ---------------------------------------------------------------------------
// k_pv (round-2 verified): mid + edge PV via fp16 MFMA, 4-way K-split,
// partial stores. grid (144, 4) x 256. bx<128: mid. bx>=128: edge.
// ---------------------------------------------------------------------------
__global__ __launch_bounds__(256) void k_pv(
    const f16* __restrict__ Pmid, const f16* __restrict__ Pedge,
    const f16* __restrict__ vhT,
    float* __restrict__ Opart, float* __restrict__ Oe)
{
    __shared__ f16 Ps[64 * 72];
    __shared__ f16 Vt[64 * 72];
    const int tid = threadIdx.x;
    const int bx  = blockIdx.x;
    const int ks  = blockIdx.y;
    const bool edge = (bx >= 128);

    const f16* Pb;
    size_t pitch;
    int row0, b, cap, cmax;
    float* outp;
    if (!edge) {
        row0 = bx * 64;
        b = row0 >> 11;
        int q0 = row0 & 2047;
        Pb = Pmid; pitch = NCOLS; cap = 34;
        cmax = (191 + q0) >> 6;
        outp = Opart + (size_t)ks * NMID * DK;
    } else {
        row0 = (bx - 128) * 64;
        b = row0 >> 8;
        int r0 = row0 & 255;
        Pb = Pedge; pitch = LE; cap = 36;
        int Qmax = (r0 < 128) ? (r0 + 63) : (2048 + r0 + 63);
        cmax = Qmax >> 6;
        outp = Oe + (size_t)ks * NEDGE * DK;
    }
    const int c_beg = ks * 9;
    int c_end = c_beg + 9;
    if (c_end > cap) c_end = cap;
    if (c_end > cmax + 1) c_end = cmax + 1;

    const int w = tid >> 6, lane = tid & 63;
    const int cl = lane & 15, quad = lane >> 4;
    f32x4 acc[4];
    #pragma unroll
    for (int c = 0; c < 4; ++c) acc[c] = 0.f;

    for (int ch = c_beg; ch < c_end; ++ch) {
        __syncthreads();
        #pragma unroll
        for (int i = 0; i < 2; ++i) {
            int g = tid + 256 * i;
            int r = g >> 3, c = g & 7;
            *(uint4*)(Ps + r * 72 + c * 8) =
                *(const uint4*)(Pb + (size_t)(row0 + r) * pitch + ch * 64 + c * 8);
            *(uint4*)(Vt + r * 72 + c * 8) =
                *(const uint4*)(vhT + (size_t)(b * 64 + r) * L_ + ch * 64 + c * 8);
        }
        __syncthreads();
        #pragma unroll
        for (int h = 0; h < 2; ++h) {
            half8 a = *(const half8*)(Ps + (16 * w + cl) * 72 + h * 32 + quad * 8);
            #pragma unroll
            for (int c = 0; c < 4; ++c) {
                half8 bv = *(const half8*)(Vt + (16 * c + cl) * 72 + h * 32 + quad * 8);
                acc[c] = __builtin_amdgcn_mfma_f32_16x16x32_f16(a, bv, acc[c], 0, 0, 0);
            }
        }
    }
    #pragma unroll
    for (int c = 0; c < 4; ++c)
        #pragma unroll
        for (int r = 0; r < 4; ++r) {
            int mrow = row0 + 16 * w + quad * 4 + r;
            int n    = 16 * c + cl;
            outp[(size_t)mrow * DK + n] = acc[c][r];
        }
}

// ---------------------------------------------------------------------------
// k_merge (round-2 verified): sum 4 partials, mid + edge. grid 2304 x 256.
// ---------------------------------------------------------------------------
__global__ __launch_bounds__(256) void k_merge(
    const float* __restrict__ Opart, const float* __restrict__ Oe,
    float* __restrict__ out)
{
    const int e = blockIdx.x * 256 + threadIdx.x;
    if (e < NMID * DK) {
        const int gr = e >> 6, c = e & 63;
        const int b  = gr >> 11, q = gr & 2047;
        const int NP = NMID * DK;
        float s = Opart[e] + Opart[e + NP] + Opart[e + 2 * NP] + Opart[e + 3 * NP];
        out[((size_t)b * L_ + S_ + q) * DK + c] = s;
    } else {
        const int e2 = e - NMID * DK;
        const int er = e2 >> 6, c = e2 & 63;
        const int b  = er >> 8, r = er & 255;
        const int gQ = (r < 128) ? r : (2048 + r);
        const int NP = NEDGE * DK;
        float s = Oe[e2] + Oe[e2 + NP] + Oe[e2 + 2 * NP] + Oe[e2 + 3 * NP];
        out[((size_t)b * L_ + gQ) * DK + c] = s;
    }
}

// ---------------------------------------------------------------------------
extern "C" void kernel_launch(void* const* d_in, const int* in_sizes, int n_in,
                              void* d_out, int out_size, void* d_ws, size_t ws_size,
                              hipStream_t stream)
{
    const float* x    = (const float*)d_in[0];
    const float* Wq   = (const float*)d_in[1];
    const float* Wk   = (const float*)d_in[2];
    const float* Wv   = (const float*)d_in[3];
    const float* Wqs  = (const float*)d_in[4];
    const float* Wks  = (const float*)d_in[5];
    const float* Wvs  = (const float*)d_in[6];
    const float* Wqe  = (const float*)d_in[7];
    const float* Wke  = (const float*)d_in[8];
    const float* Wve  = (const float*)d_in[9];
    const float* g0   = (const float*)d_in[10];
    const float* b0   = (const float*)d_in[11];
    const float* gs   = (const float*)d_in[12];
    const float* bs   = (const float*)d_in[13];
    const float* ge   = (const float*)d_in[14];
    const float* be   = (const float*)d_in[15];
    const float* cope = (const float*)d_in[16];

    const size_t NR = (size_t)B_ * L_;                 // 9216 rows
    f16*   qsp    = (f16*)d_ws;                        // NR*128 h (hi|lo)
    f16*   ksp    = qsp + NR * 128;                    // NR*128 h
    f16*   vhT    = ksp + NR * 128;                    // NR*64 h
    f16*   Wsp    = vhT + NR * 64;                     // 9*65536 h
    f16*   copesp = Wsp + (size_t)9 * 65536;           // 128*128 h
    float* G      = (float*)(copesp + 16384);          // NMID*32 f32
    float* li32   = G + (size_t)NMID * 32;             // NMID*128 f32
    float* Opart  = li32 + (size_t)NMID * 128;         // 4*NMID*64 f32
    float* Oe     = Opart + (size_t)4 * NMID * DK;     // 4*NEDGE*64 f32
    float* Dm32   = Oe + (size_t)4 * NEDGE * DK;       // NMID*NCOLS f32
    float* De32   = Dm32 + (size_t)NMID * NCOLS;       // NEDGE*LE f32
    f16*   Dp     = (f16*)(De32 + (size_t)NEDGE * LE); // NMID*NCOLS h (P)
    f16*   Dep    = Dp + (size_t)NMID * NCOLS;         // NEDGE*LE h (P)
    float* out    = (float*)d_out;

    k_wsplit<<<dim3(8, 10), 256, 0, stream>>>(Wq, Wk, Wv, Wqs, Wks, Wvs,
                                              Wqe, Wke, Wve, cope, Wsp, copesp);
    k_proj<<<288, 256, 0, stream>>>(x, Wsp, g0, b0, gs, bs, ge, be,
                                    qsp, ksp, vhT);
    k_li<<<256, 256, 0, stream>>>(qsp, copesp, li32);
    k_dots<<<dim3(72, 18), 256, 0, stream>>>(qsp, ksp, Dm32, G, De32);
    k_scan<<<NMID + NEDGE, 256, 0, stream>>>(li32, G, Dm32, Dp, De32, Dep);
    k_pv  <<<dim3(144, 4), 256, 0, stream>>>(Dp, Dep, vhT, Opart, Oe);
    k_merge<<<(NMID + NEDGE) * DK / 256, 256, 0, stream>>>(Opart, Oe, out);
}

// Round 9
// 186.459 us; speedup vs baseline: 1.3271x; 1.0301x over previous
//
#include <hip/hip_runtime.h>
#include <math.h>

#define B_    4
#define SEQ_  2048
#define S_    128
#define L_    2304          // SEQ + 2*S
#define DIN   512
#define DK    64
#define NEGINF (-1e30f)
#define SCALE 0.125f
#define NCOLS 2176          // start(128) + mid(2048) key columns in D
#define NMID  8192          // B_*SEQ_
#define NEDGE 1024          // B_*2*S_
#define LE    2304          // edge De row length

typedef _Float16 f16;
typedef __attribute__((ext_vector_type(8))) _Float16 half8;
typedef __attribute__((ext_vector_type(4))) float f32x4;

union U4 { uint4 u; f16 h[8]; half8 v; };

// ---------------------------------------------------------------------------
// k_wsplit: pre-split 9 W matrices into fp16 hi/lo (transposed) + cope split.
// grid (8, 10) x 256. mat==9: cope (64x128) -> copesp[p][hi d | lo d].
// ---------------------------------------------------------------------------
__global__ __launch_bounds__(256) void k_wsplit(
    const float* __restrict__ Wq,  const float* __restrict__ Wk,  const float* __restrict__ Wv,
    const float* __restrict__ Wqs, const float* __restrict__ Wks, const float* __restrict__ Wvs,
    const float* __restrict__ Wqe, const float* __restrict__ Wke, const float* __restrict__ Wve,
    const float* __restrict__ cope,
    f16* __restrict__ Wsp, f16* __restrict__ copesp)
{
    __shared__ float xs[64 * 68];
    const int kt  = blockIdx.x;
    const int mat = blockIdx.y;
    const int tid = threadIdx.x;

    if (mat == 9) {
        if (kt != 0) return;
        for (int half = 0; half < 2; ++half) {
            #pragma unroll
            for (int i = 0; i < 4; ++i) {
                int g = tid + 256 * i;          // 64 d x 16 float4
                int d = g >> 4, p4 = g & 15;
                *(float4*)(xs + d * 68 + p4 * 4) =
                    *(const float4*)(cope + (size_t)d * 128 + half * 64 + p4 * 4);
            }
            __syncthreads();
            if (tid < 128) {
                int pp = tid & 63, hf = tid >> 6;   // 2 halves of d
                int d0 = hf * 32;
                for (int j = 0; j < 32; ++j) {
                    float v = xs[(d0 + j) * 68 + pp];
                    f16 hi = (f16)v;
                    copesp[(size_t)(half * 64 + pp) * 128 + d0 + j]      = hi;
                    copesp[(size_t)(half * 64 + pp) * 128 + 64 + d0 + j] = (f16)(v - (float)hi);
                }
            }
            __syncthreads();
        }
        return;
    }

    const float* W;
    switch (mat) {
        case 0: W = Wq;  break; case 1: W = Wk;  break; case 2: W = Wv;  break;
        case 3: W = Wqs; break; case 4: W = Wks; break; case 5: W = Wvs; break;
        case 6: W = Wqe; break; case 7: W = Wke; break; default: W = Wve; break;
    }
    const int k0  = kt * 64;
    #pragma unroll
    for (int i = 0; i < 4; ++i) {
        int g = tid + 256 * i;
        int k = g >> 4, c4 = g & 15;
        *(float4*)(xs + k * 68 + c4 * 4) = ((const float4*)W)[(size_t)(k0 + k) * 16 + c4];
    }
    __syncthreads();
    const int col = tid & 63, hf = tid >> 6;
    const int kk0 = hf * 16;
    U4 hi0, hi1, lo0, lo1;
    #pragma unroll
    for (int j = 0; j < 8; ++j) {
        float v0 = xs[(kk0 + j) * 68 + col];
        float v1 = xs[(kk0 + 8 + j) * 68 + col];
        hi0.h[j] = (f16)v0; lo0.h[j] = (f16)(v0 - (float)hi0.h[j]);
        hi1.h[j] = (f16)v1; lo1.h[j] = (f16)(v1 - (float)hi1.h[j]);
    }
    f16* dst = Wsp + (size_t)mat * 65536 + (size_t)col * 1024 + k0 + kk0;
    *(uint4*)(dst)       = hi0.u;
    *(uint4*)(dst + 8)   = hi1.u;
    *(uint4*)(dst + 512) = lo0.u;
    *(uint4*)(dst + 520) = lo1.u;
}

// ---------------------------------------------------------------------------
// k_proj (round-2 verified): fused LayerNorm + all three projections,
// cooperative LDS staging of A and B per k-step. grid 288 x 256.
// ---------------------------------------------------------------------------
__global__ __launch_bounds__(256) void k_proj(
    const float* __restrict__ x, const f16* __restrict__ Wsp,
    const float* __restrict__ g0, const float* __restrict__ b0,
    const float* __restrict__ gs, const float* __restrict__ bs,
    const float* __restrict__ ge, const float* __restrict__ be,
    f16* __restrict__ qsp, f16* __restrict__ ksp, f16* __restrict__ vhT)
{
    __shared__ f16 As[32 * 136];       // [row][hi 0..63 | lo 64..127 | pad]
    __shared__ f16 Bs[3 * 64 * 136];   // per-mat [col][hi|lo|pad]
    __shared__ float mean_s[32], rstd_s[32];
    const int tid  = threadIdx.x;
    const int row0 = blockIdx.x * 32;
    const int rseq = row0 % L_;
    const int seg  = (rseq < S_) ? 0 : (rseq >= L_ - S_) ? 2 : 1;
    const int mat0 = (seg == 0) ? 3 : (seg == 2) ? 6 : 0;
    const float* gg = (seg == 0) ? gs : (seg == 2) ? ge : g0;
    const float* bb = (seg == 0) ? bs : (seg == 2) ? be : b0;

    // row stats: 8 threads per row, 64 elems each
    {
        const int rr = tid >> 3, qq = tid & 7;
        const float4* xr = (const float4*)(x + (size_t)(row0 + rr) * DIN) + qq * 16;
        float s = 0.f, s2 = 0.f;
        #pragma unroll
        for (int i = 0; i < 16; ++i) {
            float4 v = xr[i];
            s  += v.x + v.y + v.z + v.w;
            s2 += v.x * v.x + v.y * v.y + v.z * v.z + v.w * v.w;
        }
        s  += __shfl_xor(s, 1);  s  += __shfl_xor(s, 2);  s  += __shfl_xor(s, 4);
        s2 += __shfl_xor(s2, 1); s2 += __shfl_xor(s2, 2); s2 += __shfl_xor(s2, 4);
        if (qq == 0) {
            float mean = s * (1.f / DIN);
            mean_s[rr] = mean;
            rstd_s[rr] = rsqrtf(s2 * (1.f / DIN) - mean * mean + 1e-5f);
        }
    }

    const int w = tid >> 6, lane = tid & 63;
    const int cl = lane & 15, quad = lane >> 4;
    const int r0 = 16 * (w >> 1), c0 = 32 * (w & 1);   // wave: 16 rows x 32 cols

    f32x4 acc[3][2];
    #pragma unroll
    for (int m = 0; m < 3; ++m)
        #pragma unroll
        for (int j = 0; j < 2; ++j) acc[m][j] = 0.f;

    for (int kc = 0; kc < DIN; kc += 64) {
        __syncthreads();
        // stage A (LN'd x, hi/lo split): 32 rows x 8 col-groups = 256 units
        {
            int r = tid >> 3, c8 = tid & 7;
            const float* xp = x + (size_t)(row0 + r) * DIN + kc + c8 * 8;
            float4 a0 = *(const float4*)xp;
            float4 a1 = *(const float4*)(xp + 4);
            float4 gA = *(const float4*)(gg + kc + c8 * 8);
            float4 gB = *(const float4*)(gg + kc + c8 * 8 + 4);
            float4 bA = *(const float4*)(bb + kc + c8 * 8);
            float4 bB = *(const float4*)(bb + kc + c8 * 8 + 4);
            float mean = mean_s[r], rstd = rstd_s[r];
            float n[8];
            n[0] = (a0.x - mean) * rstd * gA.x + bA.x;
            n[1] = (a0.y - mean) * rstd * gA.y + bA.y;
            n[2] = (a0.z - mean) * rstd * gA.z + bA.z;
            n[3] = (a0.w - mean) * rstd * gA.w + bA.w;
            n[4] = (a1.x - mean) * rstd * gB.x + bB.x;
            n[5] = (a1.y - mean) * rstd * gB.y + bB.y;
            n[6] = (a1.z - mean) * rstd * gB.z + bB.z;
            n[7] = (a1.w - mean) * rstd * gB.w + bB.w;
            U4 hi, lo;
            #pragma unroll
            for (int j = 0; j < 8; ++j) {
                hi.h[j] = (f16)n[j];
                lo.h[j] = (f16)(n[j] - (float)hi.h[j]);
            }
            *(uint4*)(As + r * 136 + c8 * 8)      = hi.u;
            *(uint4*)(As + r * 136 + 64 + c8 * 8) = lo.u;
        }
        // stage B for all 3 mats: 3 x 64 cols x 8 groups = 1536 units
        #pragma unroll
        for (int i = 0; i < 6; ++i) {
            int g = tid + 256 * i;
            int mm = g >> 9, rem = g & 511;
            int col = rem >> 3, c8 = rem & 7;
            const f16* src = Wsp + (size_t)(mat0 + mm) * 65536 + (size_t)col * 1024 + kc + c8 * 8;
            f16* dst = Bs + mm * 8704 + col * 136 + c8 * 8;
            *(uint4*)(dst)      = *(const uint4*)(src);
            *(uint4*)(dst + 64) = *(const uint4*)(src + 512);
        }
        __syncthreads();
        #pragma unroll
        for (int h = 0; h < 2; ++h) {
            half8 ah, al;
            {
                const f16* base = As + (r0 + cl) * 136 + h * 32 + quad * 8;
                ah = *(const half8*)(base);
                al = *(const half8*)(base + 64);
            }
            #pragma unroll
            for (int m = 0; m < 3; ++m)
                #pragma unroll
                for (int cs = 0; cs < 2; ++cs) {
                    const f16* base = Bs + m * 8704 + (c0 + 16 * cs + cl) * 136 + h * 32 + quad * 8;
                    half8 bh = *(const half8*)(base);
                    half8 bl = *(const half8*)(base + 64);
                    acc[m][cs] = __builtin_amdgcn_mfma_f32_16x16x32_f16(ah, bh, acc[m][cs], 0, 0, 0);
                    acc[m][cs] = __builtin_amdgcn_mfma_f32_16x16x32_f16(ah, bl, acc[m][cs], 0, 0, 0);
                    acc[m][cs] = __builtin_amdgcn_mfma_f32_16x16x32_f16(al, bh, acc[m][cs], 0, 0, 0);
                }
        }
    }

    const int bI = row0 / L_;
    const int rb = row0 - bI * L_;
    #pragma unroll
    for (int m = 0; m < 3; ++m) {
        f16* sp = (m == 0) ? qsp : ksp;
        #pragma unroll
        for (int cs = 0; cs < 2; ++cs)
            #pragma unroll
            for (int r = 0; r < 4; ++r) {
                int lrow = r0 + quad * 4 + r;
                int col  = c0 + 16 * cs + cl;
                float v  = acc[m][cs][r];
                size_t grow = (size_t)(row0 + lrow);
                if (m < 2) {
                    f16 hv = (f16)v;
                    sp[grow * 128 + col]      = hv;
                    sp[grow * 128 + 64 + col] = (f16)(v - (float)hv);
                } else {
                    vhT[(size_t)(bI * 64 + col) * L_ + rb + lrow] = (f16)v;
                }
            }
    }
}

// ---------------------------------------------------------------------------
// k_dots: mid + edge dots via split-fp16 MFMA (round-2 verified core), PLUS
// li = q.cope folded into the 64 formerly-idle block slots (edge half==0,
// by 1..16). grid (72,18) x 256.
// ---------------------------------------------------------------------------
__global__ __launch_bounds__(256) void k_dots(
    const f16* __restrict__ qsp, const f16* __restrict__ ksp,
    const f16* __restrict__ copesp,
    float* __restrict__ D32, float* __restrict__ G, float* __restrict__ De32,
    float* __restrict__ li32)
{
    const int bx = blockIdx.x, by = blockIdx.y;
    const bool edge = (bx >= 64);
    const int tid = threadIdx.x;
    const int w = tid >> 6, lane = tid & 63;
    const int cl = lane & 15, quad = lane >> 4;

    int b, q0 = 0;
    size_t qrow0;
    if (!edge) {
        if (by >= 17) return;                 // NCOLS = 17 * 128
        b = bx >> 4;
        q0 = (bx * 128) & 2047;
        qrow0 = (size_t)b * L_ + S_ + q0;
    } else {
        int ex = bx - 64;
        b = ex >> 1;
        int half = ex & 1;
        if (half == 0 && by > 0) {
            // ---- li region: 64 blocks (ex in {0,2,4,6}, by 1..16) ----
            if (by > 16) return;
            const int id  = (ex >> 1) * 16 + (by - 1);   // 0..63
            const int gr0 = id * 128;
            const int lb  = gr0 >> 11, lq0 = gr0 & 2047;
            const size_t rowb = (size_t)lb * L_ + S_ + lq0 + 32 * w;

            half8 ah[2][2], al[2][2];
            #pragma unroll
            for (int rs = 0; rs < 2; ++rs)
                #pragma unroll
                for (int h = 0; h < 2; ++h) {
                    const f16* qp = qsp + (rowb + 16 * rs + cl) * 128 + h * 32 + quad * 8;
                    ah[rs][h] = *(const half8*)qp;
                    al[rs][h] = *(const half8*)(qp + 64);
                }
            f32x4 acc[2][8];
            #pragma unroll
            for (int rs = 0; rs < 2; ++rs)
                #pragma unroll
                for (int cf = 0; cf < 8; ++cf) acc[rs][cf] = 0.f;
            #pragma unroll
            for (int h = 0; h < 2; ++h)
                #pragma unroll
                for (int cf = 0; cf < 8; ++cf) {
                    const f16* bbase = copesp + (size_t)(16 * cf + cl) * 128 + h * 32 + quad * 8;
                    half8 bh = *(const half8*)bbase;
                    half8 bl = *(const half8*)(bbase + 64);
                    #pragma unroll
                    for (int rs = 0; rs < 2; ++rs) {
                        acc[rs][cf] = __builtin_amdgcn_mfma_f32_16x16x32_f16(ah[rs][h], bh, acc[rs][cf], 0, 0, 0);
                        acc[rs][cf] = __builtin_amdgcn_mfma_f32_16x16x32_f16(ah[rs][h], bl, acc[rs][cf], 0, 0, 0);
                        acc[rs][cf] = __builtin_amdgcn_mfma_f32_16x16x32_f16(al[rs][h], bh, acc[rs][cf], 0, 0, 0);
                    }
                }
            #pragma unroll
            for (int rs = 0; rs < 2; ++rs)
                #pragma unroll
                for (int cf = 0; cf < 8; ++cf)
                    #pragma unroll
                    for (int r = 0; r < 4; ++r) {
                        int row = gr0 + 32 * w + 16 * rs + quad * 4 + r;
                        li32[(size_t)row * 128 + 16 * cf + cl] = acc[rs][cf][r];
                    }
            return;
        }
        qrow0 = (size_t)b * L_ + (half ? 2176 : 0);
    }
    const int col0 = by * 128;
    const size_t krow0 = (size_t)b * L_ + col0;

    __shared__ f16 Qs[128 * 136];
    __shared__ f16 Ks[128 * 136];

    #pragma unroll
    for (int i = 0; i < 8; ++i) {
        int g = tid + 256 * i;
        int r = g >> 4, c = g & 15;
        *(uint4*)(Qs + r * 136 + c * 8) = *(const uint4*)(qsp + (qrow0 + r) * 128 + c * 8);
        *(uint4*)(Ks + r * 136 + c * 8) = *(const uint4*)(ksp + (krow0 + r) * 128 + c * 8);
    }
    __syncthreads();

    f32x4 acc[2][8];
    #pragma unroll
    for (int i = 0; i < 2; ++i)
        #pragma unroll
        for (int j = 0; j < 8; ++j) acc[i][j] = 0.f;

    #pragma unroll
    for (int h = 0; h < 2; ++h) {
        half8 ah[2], al[2];
        #pragma unroll
        for (int rs = 0; rs < 2; ++rs) {
            const f16* base = Qs + (32 * w + 16 * rs + cl) * 136 + h * 32 + quad * 8;
            ah[rs] = *(const half8*)(base);
            al[rs] = *(const half8*)(base + 64);
        }
        #pragma unroll
        for (int cq = 0; cq < 2; ++cq) {
            half8 bh[4], bl[4];
            #pragma unroll
            for (int cc = 0; cc < 4; ++cc) {
                const f16* base = Ks + (16 * (cq * 4 + cc) + cl) * 136 + h * 32 + quad * 8;
                bh[cc] = *(const half8*)(base);
                bl[cc] = *(const half8*)(base + 64);
            }
            #pragma unroll
            for (int rs = 0; rs < 2; ++rs)
                #pragma unroll
                for (int cc = 0; cc < 4; ++cc) {
                    int c = cq * 4 + cc;
                    acc[rs][c] = __builtin_amdgcn_mfma_f32_16x16x32_f16(ah[rs], bh[cc], acc[rs][c], 0, 0, 0);
                    acc[rs][c] = __builtin_amdgcn_mfma_f32_16x16x32_f16(ah[rs], bl[cc], acc[rs][c], 0, 0, 0);
                    acc[rs][c] = __builtin_amdgcn_mfma_f32_16x16x32_f16(al[rs], bh[cc], acc[rs][c], 0, 0, 0);
                }
        }
    }

    if (!edge) {
        const int gr0 = bx * 128;
        const bool writeD = (by == 0) || ((by - 1) <= (q0 >> 7));
        if (writeD) {
            #pragma unroll
            for (int rs = 0; rs < 2; ++rs)
                #pragma unroll
                for (int c = 0; c < 8; ++c)
                    #pragma unroll
                    for (int r = 0; r < 4; ++r) {
                        int mrow = gr0 + 32 * w + 16 * rs + quad * 4 + r;
                        int n    = col0 + 16 * c + cl;
                        D32[(size_t)mrow * NCOLS + n] = acc[rs][c][r];
                    }
        }
        if (by >= 1) {
            const int chm = 2 * (by - 1);
            #pragma unroll
            for (int rs = 0; rs < 2; ++rs)
                #pragma unroll
                for (int r = 0; r < 4; ++r) {
                    float sA = 0.f, sB = 0.f;
                    #pragma unroll
                    for (int cc = 0; cc < 4; ++cc) {
                        sA += 1.f / (1.f + __expf(-acc[rs][cc][r]));
                        sB += 1.f / (1.f + __expf(-acc[rs][4 + cc][r]));
                    }
                    #pragma unroll
                    for (int off = 1; off < 16; off <<= 1) {
                        sA += __shfl_xor(sA, off);
                        sB += __shfl_xor(sB, off);
                    }
                    if (cl == 0) {
                        int row = gr0 + 32 * w + 16 * rs + quad * 4 + r;
                        G[(size_t)row * 32 + chm]     = sA;
                        G[(size_t)row * 32 + chm + 1] = sB;
                    }
                }
        }
    } else {
        const int er0 = (bx - 64) * 128;
        #pragma unroll
        for (int rs = 0; rs < 2; ++rs)
            #pragma unroll
            for (int c = 0; c < 8; ++c)
                #pragma unroll
                for (int r = 0; r < 4; ++r) {
                    int erow = er0 + 32 * w + 16 * rs + quad * 4 + r;
                    int n    = col0 + 16 * c + cl;
                    De32[(size_t)erow * LE + n] = acc[rs][c][r];
                }
    }
}

// ---------------------------------------------------------------------------
// k_scan: grid 9216 x 256. Reads exact fp32 dots + precomputed li; fp16 P.
// Edge path: loads predicated on causal bound (start rows skip 8/9 groups).
// ---------------------------------------------------------------------------
__global__ __launch_bounds__(256) void k_scan(
    const float* __restrict__ li32, const float* __restrict__ G,
    const float* __restrict__ D32, f16* __restrict__ Dp,
    const float* __restrict__ De32, f16* __restrict__ Dep)
{
    __shared__ float li[128];
    __shared__ float Gs[32];
    __shared__ float Gsf[32];
    __shared__ float wmax[4], wsum[4];
    const int tid = threadIdx.x;
    const int gr  = blockIdx.x;
    const int lane = tid & 63, wid = tid >> 6;

    if (gr < NMID) {
        const int b = gr >> 11;
        const int q = gr & 2047;
        const int qlim = (q & ~63) + 64;

        if (tid < 128) li[tid] = li32[(size_t)gr * 128 + tid];
        if (tid >= 128 && tid < 136)
            ((float4*)Gs)[tid - 128] = ((const float4*)G)[(size_t)gr * 8 + tid - 128];
        __syncthreads();
        if (tid >= 128 && tid < 160) {
            int c = tid - 128;
            float s = 0.f;
            for (int cc = c + 1; cc < 32; ++cc) s += Gs[cc];
            Gsf[c] = s;
        }

        const float* Sr = D32 + (size_t)gr * NCOLS;
        f16* Dr = Dp + (size_t)gr * NCOLS;
        const int j0 = tid * 8;
        const int cg = tid >> 3, sl = tid & 7;
        float dot[8], gte[8];
        float csum = 0.f;
        if (j0 < qlim) {
            float4 t0 = *(const float4*)(Sr + 128 + j0);
            float4 t1 = *(const float4*)(Sr + 128 + j0 + 4);
            dot[0] = t0.x; dot[1] = t0.y; dot[2] = t0.z; dot[3] = t0.w;
            dot[4] = t1.x; dot[5] = t1.y; dot[6] = t1.z; dot[7] = t1.w;
            #pragma unroll
            for (int jj = 0; jj < 8; ++jj) {
                gte[jj] = 1.f / (1.f + __expf(-dot[jj]));
                csum += gte[jj];
            }
        } else {
            #pragma unroll
            for (int jj = 0; jj < 8; ++jj) { dot[jj] = 0.f; gte[jj] = 0.f; }
        }
        float sv = (tid < 128) ? Sr[tid] * SCALE : NEGINF;

        float inc = csum;
        #pragma unroll
        for (int off = 1; off < 8; off <<= 1) {
            float u = __shfl_down(inc, off, 8);
            if (sl + off < 8) inc += u;
        }
        __syncthreads();
        float run = (inc - csum) + Gsf[cg];

        float p8[8];
        #pragma unroll
        for (int jj = 7; jj >= 0; --jj) {
            run += gte[jj];
            float pos = fminf(run, (float)(S_ - 1));
            float pfl = floorf(pos);
            int ic  = (int)ceilf(pos);
            int ifl = (int)pfl;
            float w = pos - pfl;
            float bias = li[ic] * w + li[ifl] * (1.f - w);
            p8[jj] = (j0 + jj <= q) ? dot[jj] * SCALE + bias : NEGINF;
        }

        float mx = sv;
        #pragma unroll
        for (int jj = 0; jj < 8; ++jj) mx = fmaxf(mx, p8[jj]);
        #pragma unroll
        for (int off = 1; off < 64; off <<= 1) mx = fmaxf(mx, __shfl_xor(mx, off));
        if (lane == 0) wmax[wid] = mx;
        __syncthreads();
        mx = fmaxf(fmaxf(wmax[0], wmax[1]), fmaxf(wmax[2], wmax[3]));

        float lsum = 0.f;
        float e8[8];
        #pragma unroll
        for (int jj = 0; jj < 8; ++jj) {
            e8[jj] = __expf(p8[jj] - mx);
            lsum += e8[jj];
        }
        float es = 0.f;
        if (tid < 128) { es = __expf(sv - mx); lsum += es; }
        #pragma unroll
        for (int off = 1; off < 64; off <<= 1) lsum += __shfl_xor(lsum, off);
        if (lane == 0) wsum[wid] = lsum;
        __syncthreads();
        float inv = 1.f / (wsum[0] + wsum[1] + wsum[2] + wsum[3]);

        if (j0 < qlim) {
            U4 o;
            #pragma unroll
            for (int jj = 0; jj < 8; ++jj) o.h[jj] = (f16)(e8[jj] * inv);
            *(uint4*)(Dr + 128 + j0) = o.u;
        }
        if (tid < 128) Dr[tid] = (f16)(es * inv);
    } else {
        const int er = gr - NMID;
        const int r  = er & 255;
        const int Q  = (r < 128) ? r : (2048 + r);
        const float* Er32 = De32 + (size_t)er * LE;
        f16* Er = Dep + (size_t)er * LE;

        float v[9];
        #pragma unroll
        for (int i = 0; i < 9; ++i) {
            int j = tid + 256 * i;
            v[i] = (j <= Q) ? Er32[j] * SCALE : NEGINF;   // predicated load
        }
        float mx = v[0];
        #pragma unroll
        for (int i = 1; i < 9; ++i) mx = fmaxf(mx, v[i]);
        #pragma unroll
        for (int off = 1; off < 64; off <<= 1) mx = fmaxf(mx, __shfl_xor(mx, off));
        if (lane == 0) wmax[wid] = mx;
        __syncthreads();
        mx = fmaxf(fmaxf(wmax[0], wmax[1]), fmaxf(wmax[2], wmax[3]));

        float lsum = 0.f;
        #pragma unroll
        for (int i = 0; i < 9; ++i) {
            v[i] = __expf(v[i] - mx);
            lsum += v[i];
        }
        #pragma unroll
        for (int off = 1; off < 64; off <<= 1) lsum += __shfl_xor(lsum, off);
        if (lane == 0) wsum[wid] = lsum;
        __syncthreads();
        float inv = 1.f / (wsum[0] + wsum[1] + wsum[2] + wsum[3]);

        #pragma unroll
        for (int i = 0; i < 9; ++i)
            Er[tid + 256 * i] = (f16)(v[i] * inv);
    }
}

// ---------------------------------------------------------------------------
// k_pv (round-2 verified): mid + edge PV via fp16 MFMA, 4-way K-split,
// partial stores. grid (144, 4) x 256. bx<128: mid. bx>=128: edge.
// ---------------------------------------------------------------------------
__global__ __launch_bounds__(256) void k_pv(
    const f16* __restrict__ Pmid, const f16* __restrict__ Pedge,
    const f16* __restrict__ vhT,
    float* __restrict__ Opart, float* __restrict__ Oe)
{
    __shared__ f16 Ps[64 * 72];
    __shared__ f16 Vt[64 * 72];
    const int tid = threadIdx.x;
    const int bx  = blockIdx.x;
    const int ks  = blockIdx.y;
    const bool edge = (bx >= 128);

    const f16* Pb;
    size_t pitch;
    int row0, b, cap, cmax;
    float* outp;
    if (!edge) {
        row0 = bx * 64;
        b = row0 >> 11;
        int q0 = row0 & 2047;
        Pb = Pmid; pitch = NCOLS; cap = 34;
        cmax = (191 + q0) >> 6;
        outp = Opart + (size_t)ks * NMID * DK;
    } else {
        row0 = (bx - 128) * 64;
        b = row0 >> 8;
        int r0 = row0 & 255;
        Pb = Pedge; pitch = LE; cap = 36;
        int Qmax = (r0 < 128) ? (r0 + 63) : (2048 + r0 + 63);
        cmax = Qmax >> 6;
        outp = Oe + (size_t)ks * NEDGE * DK;
    }
    const int c_beg = ks * 9;
    int c_end = c_beg + 9;
    if (c_end > cap) c_end = cap;
    if (c_end > cmax + 1) c_end = cmax + 1;

    const int w = tid >> 6, lane = tid & 63;
    const int cl = lane & 15, quad = lane >> 4;
    f32x4 acc[4];
    #pragma unroll
    for (int c = 0; c < 4; ++c) acc[c] = 0.f;

    for (int ch = c_beg; ch < c_end; ++ch) {
        __syncthreads();
        #pragma unroll
        for (int i = 0; i < 2; ++i) {
            int g = tid + 256 * i;
            int r = g >> 3, c = g & 7;
            *(uint4*)(Ps + r * 72 + c * 8) =
                *(const uint4*)(Pb + (size_t)(row0 + r) * pitch + ch * 64 + c * 8);
            *(uint4*)(Vt + r * 72 + c * 8) =
                *(const uint4*)(vhT + (size_t)(b * 64 + r) * L_ + ch * 64 + c * 8);
        }
        __syncthreads();
        #pragma unroll
        for (int h = 0; h < 2; ++h) {
            half8 a = *(const half8*)(Ps + (16 * w + cl) * 72 + h * 32 + quad * 8);
            #pragma unroll
            for (int c = 0; c < 4; ++c) {
                half8 bv = *(const half8*)(Vt + (16 * c + cl) * 72 + h * 32 + quad * 8);
                acc[c] = __builtin_amdgcn_mfma_f32_16x16x32_f16(a, bv, acc[c], 0, 0, 0);
            }
        }
    }
    #pragma unroll
    for (int c = 0; c < 4; ++c)
        #pragma unroll
        for (int r = 0; r < 4; ++r) {
            int mrow = row0 + 16 * w + quad * 4 + r;
            int n    = 16 * c + cl;
            outp[(size_t)mrow * DK + n] = acc[c][r];
        }
}

// ---------------------------------------------------------------------------
// k_merge (round-2 verified): sum 4 partials, mid + edge. grid 2304 x 256.
// ---------------------------------------------------------------------------
__global__ __launch_bounds__(256) void k_merge(
    const float* __restrict__ Opart, const float* __restrict__ Oe,
    float* __restrict__ out)
{
    const int e = blockIdx.x * 256 + threadIdx.x;
    if (e < NMID * DK) {
        const int gr = e >> 6, c = e & 63;
        const int b  = gr >> 11, q = gr & 2047;
        const int NP = NMID * DK;
        float s = Opart[e] + Opart[e + NP] + Opart[e + 2 * NP] + Opart[e + 3 * NP];
        out[((size_t)b * L_ + S_ + q) * DK + c] = s;
    } else {
        const int e2 = e - NMID * DK;
        const int er = e2 >> 6, c = e2 & 63;
        const int b  = er >> 8, r = er & 255;
        const int gQ = (r < 128) ? r : (2048 + r);
        const int NP = NEDGE * DK;
        float s = Oe[e2] + Oe[e2 + NP] + Oe[e2 + 2 * NP] + Oe[e2 + 3 * NP];
        out[((size_t)b * L_ + gQ) * DK + c] = s;
    }
}

// ---------------------------------------------------------------------------
extern "C" void kernel_launch(void* const* d_in, const int* in_sizes, int n_in,
                              void* d_out, int out_size, void* d_ws, size_t ws_size,
                              hipStream_t stream)
{
    const float* x    = (const float*)d_in[0];
    const float* Wq   = (const float*)d_in[1];
    const float* Wk   = (const float*)d_in[2];
    const float* Wv   = (const float*)d_in[3];
    const float* Wqs  = (const float*)d_in[4];
    const float* Wks  = (const float*)d_in[5];
    const float* Wvs  = (const float*)d_in[6];
    const float* Wqe  = (const float*)d_in[7];
    const float* Wke  = (const float*)d_in[8];
    const float* Wve  = (const float*)d_in[9];
    const float* g0   = (const float*)d_in[10];
    const float* b0   = (const float*)d_in[11];
    const float* gs   = (const float*)d_in[12];
    const float* bs   = (const float*)d_in[13];
    const float* ge   = (const float*)d_in[14];
    const float* be   = (const float*)d_in[15];
    const float* cope = (const float*)d_in[16];

    const size_t NR = (size_t)B_ * L_;                 // 9216 rows
    f16*   qsp    = (f16*)d_ws;                        // NR*128 h (hi|lo)
    f16*   ksp    = qsp + NR * 128;                    // NR*128 h
    f16*   vhT    = ksp + NR * 128;                    // NR*64 h
    f16*   Wsp    = vhT + NR * 64;                     // 9*65536 h
    f16*   copesp = Wsp + (size_t)9 * 65536;           // 128*128 h
    float* G      = (float*)(copesp + 16384);          // NMID*32 f32
    float* li32   = G + (size_t)NMID * 32;             // NMID*128 f32
    float* Opart  = li32 + (size_t)NMID * 128;         // 4*NMID*64 f32
    float* Oe     = Opart + (size_t)4 * NMID * DK;     // 4*NEDGE*64 f32
    float* Dm32   = Oe + (size_t)4 * NEDGE * DK;       // NMID*NCOLS f32
    float* De32   = Dm32 + (size_t)NMID * NCOLS;       // NEDGE*LE f32
    f16*   Dp     = (f16*)(De32 + (size_t)NEDGE * LE); // NMID*NCOLS h (P)
    f16*   Dep    = Dp + (size_t)NMID * NCOLS;         // NEDGE*LE h (P)
    float* out    = (float*)d_out;

    k_wsplit<<<dim3(8, 10), 256, 0, stream>>>(Wq, Wk, Wv, Wqs, Wks, Wvs,
                                              Wqe, Wke, Wve, cope, Wsp, copesp);
    k_proj<<<288, 256, 0, stream>>>(x, Wsp, g0, b0, gs, bs, ge, be,
                                    qsp, ksp, vhT);
    k_dots<<<dim3(72, 18), 256, 0, stream>>>(qsp, ksp, copesp, Dm32, G, De32, li32);
    k_scan<<<NMID + NEDGE, 256, 0, stream>>>(li32, G, Dm32, Dp, De32, Dep);
    k_pv  <<<dim3(144, 4), 256, 0, stream>>>(Dp, Dep, vhT, Opart, Oe);
    k_merge<<<(NMID + NEDGE) * DK / 256, 256, 0, stream>>>(Opart, Oe, out);
}